// Round 14
// baseline (547.635 us; speedup 1.0000x reference)
//
#include <hip/hip_runtime.h>
#include <cmath>

// ---- problem constants ----
#define WD 128
#define HT 128
#define HW 16384            // H*W
#define NB 4
#define NA 9
#define NPB (NA*HW)         // anchors per batch = 147456
#define TOPN 4000
#define POSTN 1000
#define CANDCAP 8192        // max candidates per batch (fine-bin overshoot << this)
#define MROWS 4096          // padded rows for topk buffer
#define RST 4160            // row stride (u64s) per (b,word) mask stream
#define NTILE 63            // ceil(4000/64)
#define TRI (NTILE*(NTILE+1)/2)   // 2016 upper-triangle tiles
#define NREP 4              // histogram replicas (contention divider)
#define PBLK 576            // 256-thread blocks per batch (NPB/256)
#define NBLK 42             // LDS-staged column blocks (covers exit <= chunk 42)

typedef unsigned long long u64;
typedef unsigned int u32;

struct Anchors { float v[36]; };

// ---------------- host: replicate numpy _generate_anchors exactly ----------------
static void gen_anchors(float* out) {
    double base[4] = {0.0, 0.0, 15.0, 15.0};
    const double ratios[3] = {0.5, 1.0, 2.0};
    const double scales[3] = {8.0, 16.0, 32.0};
    double w = base[2] - base[0] + 1.0;
    double h = base[3] - base[1] + 1.0;
    double xc = base[0] + 0.5 * (w - 1.0);
    double yc = base[1] + 0.5 * (h - 1.0);
    double size = w * h;
    double ra[3][4];
    for (int r = 0; r < 3; ++r) {
        double ws = nearbyint(sqrt(size / ratios[r]));   // np.round = half-even
        double hs = nearbyint(ws * ratios[r]);
        ra[r][0] = xc - 0.5 * (ws - 1.0);
        ra[r][1] = yc - 0.5 * (hs - 1.0);
        ra[r][2] = xc + 0.5 * (ws - 1.0);
        ra[r][3] = yc + 0.5 * (hs - 1.0);
    }
    int k = 0;
    for (int r = 0; r < 3; ++r) {
        double w2 = ra[r][2] - ra[r][0] + 1.0;
        double h2 = ra[r][3] - ra[r][1] + 1.0;
        double x2c = ra[r][0] + 0.5 * (w2 - 1.0);
        double y2c = ra[r][1] + 0.5 * (h2 - 1.0);
        for (int s = 0; s < 3; ++s) {
            double ws = w2 * scales[s], hs = h2 * scales[s];
            out[k*4+0] = (float)(x2c - 0.5 * (ws - 1.0));
            out[k*4+1] = (float)(y2c - 0.5 * (hs - 1.0));
            out[k*4+2] = (float)(x2c + 0.5 * (ws - 1.0));
            out[k*4+3] = (float)(y2c + 0.5 * (hs - 1.0));
            ++k;
        }
    }
}

__device__ __forceinline__ u32 sortable_key(float sc) {
    u32 sb = __float_as_uint(sc);
    return sb ^ ((sb & 0x80000000u) ? 0xFFFFFFFFu : 0x80000000u);
}

__device__ __forceinline__ u64 readlane64(u64 v, int l) {
    u32 lo = (u32)__builtin_amdgcn_readlane((int)(u32)v, l);
    u32 hi = (u32)__builtin_amdgcn_readlane((int)(u32)(v >> 32), l);
    return ((u64)hi << 32) | lo;
}

// 64-lane OR-reduce on the VALU pipe via DPP (rocPRIM pattern).
__device__ __forceinline__ u64 wave_or64_dpp(u64 v) {
    u32 lo = (u32)v, hi = (u32)(v >> 32);
#define DPPOR(x, ctrl) x |= (u32)__builtin_amdgcn_update_dpp(0, (int)(x), ctrl, 0xf, 0xf, false)
    DPPOR(lo, 0x111); DPPOR(lo, 0x112); DPPOR(lo, 0x114); DPPOR(lo, 0x118);
    DPPOR(lo, 0x142); DPPOR(lo, 0x143);
    DPPOR(hi, 0x111); DPPOR(hi, 0x112); DPPOR(hi, 0x114); DPPOR(hi, 0x118);
    DPPOR(hi, 0x142); DPPOR(hi, 0x143);
#undef DPPOR
    u32 rlo = (u32)__builtin_amdgcn_readlane((int)lo, 63);
    u32 rhi = (u32)__builtin_amdgcn_readlane((int)hi, 63);
    return ((u64)rhi << 32) | rlo;
}

// Shared decode: used by k_props (filter) and k_rank2 (winner gather).
// Same source + contract(off) in both -> bit-identical boxes.
__device__ __forceinline__ float4 decode_box(const float* __restrict__ deltas,
                                             const float* __restrict__ im_info,
                                             const Anchors& A, int b, int a, int p)
{
#pragma clang fp contract(off)
    int hh = p >> 7;        // / W
    int ww = p & 127;       // % W
    float sx = (float)(ww * 16);
    float sy = (float)(hh * 16);
    float ax1 = A.v[a*4+0] + sx;
    float ay1 = A.v[a*4+1] + sy;
    float ax2 = A.v[a*4+2] + sx;
    float ay2 = A.v[a*4+3] + sy;
    const float* dbase = deltas + ((size_t)(b*36 + a*4))*HW + p;
    float dx = dbase[0];
    float dy = dbase[HW];
    float dw = dbase[2*HW];
    float dh = dbase[3*HW];
    float aw = ax2 - ax1 + 1.0f;
    float ah = ay2 - ay1 + 1.0f;
    float cx = ax1 + 0.5f*aw;
    float cy = ay1 + 0.5f*ah;
    float pcx = dx*aw + cx;
    float pcy = dy*ah + cy;
    float ew = (float)exp((double)dw);   // correctly-rounded f32 exp
    float eh = (float)exp((double)dh);
    float pw = ew * aw;
    float ph = eh * ah;
    float x1 = pcx - 0.5f*pw;
    float y1 = pcy - 0.5f*ph;
    float x2 = pcx + 0.5f*pw;
    float y2 = pcy + 0.5f*ph;
    float hmax = im_info[b*3+0] - 1.0f;
    float wmax = im_info[b*3+1] - 1.0f;
    x1 = fmaxf(x1, 0.0f); y1 = fmaxf(y1, 0.0f);
    x2 = fmaxf(x2, 0.0f); y2 = fmaxf(y2, 0.0f);
    x1 = fminf(x1, wmax); y1 = fminf(y1, hmax);
    x2 = fminf(x2, wmax); y2 = fminf(y2, hmax);
    return make_float4(x1, y1, x2, y2);
}

// ---------------- kernel 1: decode + coarse hist; LAST BLOCK runs findA ----------------
__global__ void k_props(const float* __restrict__ scores,
                        const float* __restrict__ deltas,
                        const float* __restrict__ im_info,
                        const float* __restrict__ valid_range,
                        Anchors A,
                        u32* __restrict__ fkeys,
                        u32* __restrict__ coarseH,   // [NREP][NB][256]
                        int* __restrict__ cstar, u32* __restrict__ cabove,
                        u32* __restrict__ done)
{
#pragma clang fp contract(off)
    __shared__ u32 lh[256];
    __shared__ u32 isLast;
    __shared__ u32 sfx[256];
    int tid = threadIdx.x;
    lh[tid] = 0;
    __syncthreads();

    int n = blockIdx.x * 256 + tid;
    int b = n / NPB;
    int r = n - b*NPB;
    int a = r / HW;
    int p = r - a*HW;

    float4 bx = decode_box(deltas, im_info, A, b, a, p);
    float sc = scores[((size_t)(b*18 + 9 + a))*HW + p];
    float width  = bx.z - bx.x;
    float height = bx.w - bx.y;
    float area = width * height;
    float v0 = valid_range[b*2+0], v1 = valid_range[b*2+1];
    if (area < v0*v0 || area > v1*v1) sc = -1.0f;

    u32 key = sortable_key(sc);
    fkeys[n] = key;
    atomicAdd(&lh[key >> 24], 1u);
    __syncthreads();

    u32 v = lh[tid];
    if (v) {
        int rep = blockIdx.x & (NREP-1);
        atomicAdd(&coarseH[((size_t)rep*NB + b)*256 + tid], v);
    }

    // ---- last-block-done -> findA (parallel suffix-sum) ----
    __threadfence();
    __syncthreads();
    if (tid == 0) isLast = (atomicAdd(done, 1u) == (u32)(gridDim.x - 1)) ? 1u : 0u;
    __syncthreads();
    if (!isLast) return;
    __threadfence();
    for (int bb = 0; bb < NB; ++bb) {
        u32 s = 0;
        for (int rr = 0; rr < NREP; ++rr) s += coarseH[((size_t)rr*NB + bb)*256 + tid];
        sfx[tid] = s;
        __syncthreads();
        for (int d = 1; d < 256; d <<= 1) {
            u32 add = (tid + d < 256) ? sfx[tid + d] : 0u;
            __syncthreads();
            sfx[tid] += add;
            __syncthreads();
        }
        u32 mine = sfx[tid];
        u32 nxt  = (tid < 255) ? sfx[tid+1] : 0u;
        if (mine >= TOPN && (tid == 255 || nxt < TOPN)) { cstar[bb] = tid; cabove[bb] = nxt; }
        __syncthreads();
    }
}

// ---------------- kernel 2: fine hist within coarse bin; LAST BLOCK runs findB ----------------
__global__ void k_fineHist(const u32* __restrict__ fkeys,
                           const int* __restrict__ cstar, const u32* __restrict__ cabove,
                           u32* __restrict__ fineH,     // [NREP][NB][256]
                           u32* __restrict__ thresh16,
                           u32* __restrict__ done)
{
    __shared__ u32 isLast;
    __shared__ u32 sfx[256];
    int tid = threadIdx.x;
    int n = blockIdx.x * 256 + tid;
    int b = n / NPB;
    u32 key = fkeys[n];
    if ((int)(key >> 24) == cstar[b]) {
        int rep = blockIdx.x & (NREP-1);
        atomicAdd(&fineH[((size_t)rep*NB + b)*256 + ((key >> 16) & 255u)], 1u);
    }
    __threadfence();
    __syncthreads();
    if (tid == 0) isLast = (atomicAdd(done, 1u) == (u32)(gridDim.x - 1)) ? 1u : 0u;
    __syncthreads();
    if (!isLast) return;
    __threadfence();
    for (int bb = 0; bb < NB; ++bb) {
        u32 s = 0;
        for (int rr = 0; rr < NREP; ++rr) s += fineH[((size_t)rr*NB + bb)*256 + tid];
        sfx[tid] = s;
        __syncthreads();
        for (int d = 1; d < 256; d <<= 1) {
            u32 add = (tid + d < 256) ? sfx[tid + d] : 0u;
            __syncthreads();
            sfx[tid] += add;
            __syncthreads();
        }
        u32 ca   = cabove[bb];
        u32 mine = ca + sfx[tid];
        u32 nxt  = (tid < 255) ? (ca + sfx[tid+1]) : ca;
        if (mine >= TOPN && (tid == 255 || nxt < TOPN))
            thresh16[bb] = ((u32)cstar[bb] << 8) | (u32)tid;
        __syncthreads();
    }
}

// ---------------- kernel 3: per-block counts; LAST BLOCK runs the 576-scan ----------------
__global__ void k_count(const u32* __restrict__ fkeys,
                        const u32* __restrict__ thresh16,
                        u32* __restrict__ bcnt, u32* __restrict__ bbase,
                        u32* __restrict__ ccnt, u32* __restrict__ done)
{
    __shared__ u32 wc[4];
    __shared__ u32 isLast;
    __shared__ u32 part[256];
    int tid = threadIdx.x;
    int n = blockIdx.x * 256 + tid;
    int b = n / NPB;
    bool cond = (fkeys[n] >> 16) >= thresh16[b];
    u64 m = __ballot(cond);
    int wave = tid >> 6;
    if ((tid & 63) == 0) wc[wave] = (u32)__popcll(m);
    __syncthreads();
    if (tid == 0) atomicExch(&bcnt[blockIdx.x], wc[0]+wc[1]+wc[2]+wc[3]);  // coherent store
    __threadfence();
    __syncthreads();
    if (tid == 0) isLast = (atomicAdd(done, 1u) == (u32)(gridDim.x - 1)) ? 1u : 0u;
    __syncthreads();
    if (!isLast) return;
    __threadfence();
    // exclusive scan of 576 block-counts per batch, 256 threads (t<192 own 3 each)
    for (int bb = 0; bb < NB; ++bb) {
        u32 a0 = 0, a1 = 0, a2 = 0;
        int base = bb*PBLK + tid*3;
        if (tid < 192) { a0 = bcnt[base]; a1 = bcnt[base+1]; a2 = bcnt[base+2]; }
        u32 s3 = a0 + a1 + a2;
        part[tid] = s3;
        __syncthreads();
        for (int d = 1; d < 256; d <<= 1) {
            u32 add = (tid >= d) ? part[tid - d] : 0u;
            __syncthreads();
            part[tid] += add;
            __syncthreads();
        }
        u32 excl = part[tid] - s3;
        if (tid < 192) {
            bbase[base]   = excl;
            bbase[base+1] = excl + a0;
            bbase[base+2] = excl + a0 + a1;
        }
        if (tid == 255) ccnt[bb] = part[255];
        __syncthreads();
    }
}

// ---------------- kernel 4: emit candidates at deterministic positions ----------------
__global__ void k_emit(const u32* __restrict__ fkeys,
                       const u32* __restrict__ thresh16,
                       const u32* __restrict__ bbase,
                       u64* __restrict__ cand)
{
    __shared__ u32 wb[4];
    int tid = threadIdx.x;
    int n = blockIdx.x * 256 + tid;
    int b = n / NPB;
    int r = n - b*NPB;
    int a = r / HW;
    int p = r - a*HW;
    u32 key = fkeys[n];
    bool cond = (key >> 16) >= thresh16[b];
    u64 m = __ballot(cond);
    int lane = tid & 63;
    int wave = tid >> 6;
    if (lane == 0) wb[wave] = (u32)__popcll(m);
    __syncthreads();
    if (cond) {
        u32 wbase = 0;
        for (int wv = 0; wv < wave; ++wv) wbase += wb[wv];
        u32 off = (u32)__popcll(m & ((1ull << lane) - 1ull));
        u32 pos = bbase[blockIdx.x] + wbase + off;
        if (pos < CANDCAP) {
            u32 t = (u32)(p*NA + a);               // reference flat index
            cand[(size_t)b*CANDCAP + pos] = ((u64)key << 32) | (u32)(~t);
        }
    }
}

// ---------------- kernel 5: global rank-sort in LDS + winner re-decode ----------------
__global__ void k_rank2(const u64* __restrict__ cand, const u32* __restrict__ ccnt,
                        const float* __restrict__ deltas,
                        const float* __restrict__ im_info,
                        Anchors A,
                        float4* __restrict__ topk)
{
    __shared__ u64 kk[CANDCAP];   // 64 KB
    __shared__ u32 ps[256];
    int b = blockIdx.y;
    u32 N = ccnt[b]; if (N > CANDCAP) N = CANDCAP;
    int tid = threadIdx.x;
    if ((u32)(blockIdx.x * 64) >= N) return;    // whole block idle
    for (u32 i = tid; i < N; i += 256) kk[i] = cand[(size_t)b*CANDCAP + i];
    __syncthreads();
    int kl = tid & 63, seg = tid >> 6;
    u32 ki = (u32)(blockIdx.x * 64 + kl);
    u64 mykey = (ki < N) ? kk[ki] : ~0ull;
    u32 segN = (N + 3) >> 2;
    u32 s0 = seg * segN;
    u32 s1 = s0 + segN; if (s1 > N) s1 = N;
    u32 pr = 0;
    u32 i = s0;
    for (; i + 16 <= s1; i += 16) {
        u64 v0 = kk[i+0],  v1 = kk[i+1],  v2 = kk[i+2],  v3 = kk[i+3];
        u64 v4 = kk[i+4],  v5 = kk[i+5],  v6 = kk[i+6],  v7 = kk[i+7];
        u64 v8 = kk[i+8],  v9 = kk[i+9],  va = kk[i+10], vb = kk[i+11];
        u64 vc = kk[i+12], vd = kk[i+13], ve = kk[i+14], vf = kk[i+15];
        pr += (v0 > mykey) + (v1 > mykey) + (v2 > mykey) + (v3 > mykey);
        pr += (v4 > mykey) + (v5 > mykey) + (v6 > mykey) + (v7 > mykey);
        pr += (v8 > mykey) + (v9 > mykey) + (va > mykey) + (vb > mykey);
        pr += (vc > mykey) + (vd > mykey) + (ve > mykey) + (vf > mykey);
    }
    for (; i < s1; ++i) pr += (kk[i] > mykey) ? 1u : 0u;
    ps[tid] = pr;
    __syncthreads();
    if (seg == 0 && ki < N) {
        u32 rank = ps[kl] + ps[kl+64] + ps[kl+128] + ps[kl+192];
        if (rank < TOPN) {
            u32 t = ~((u32)mykey);
            int a = (int)(t % 9u);
            int p = (int)(t / 9u);
            topk[(size_t)b*MROWS + rank] = decode_box(deltas, im_info, A, b, a, p);
        }
    }
}

// ---------------- kernel 6: suppression-mask tiles — UPPER TRIANGLE ONLY ----------------
// k_nms reads only tj >= ti blocks (column pull: blocks k<=c of column c).
__global__ void k_mask(const float4* __restrict__ topk, u64* __restrict__ masksT)
{
#pragma clang fp contract(off)
    int L = blockIdx.x;            // 0..TRI-1
    int b = blockIdx.y;
    int ti = (int)((2.0*NTILE + 1.0 -
                    sqrt((2.0*NTILE + 1.0)*(2.0*NTILE + 1.0) - 8.0*(double)L)) * 0.5);
    while ((ti+1)*NTILE - ((ti+1)*ti)/2 <= L) ++ti;          // fixup sqrt rounding
    while (ti*NTILE - (ti*(ti-1))/2 > L) --ti;
    int tj = ti + (L - (ti*NTILE - (ti*(ti-1))/2));

    int r = threadIdx.x;           // 0..63
    int i = ti*64 + r;
    __shared__ float4 cb[64];
    __shared__ float  ca[64];
    u64 word = 0;
    {
        int jj = tj*64 + r;
        float4 cbox = (jj < TOPN) ? topk[(size_t)b*MROWS + jj] : make_float4(0,0,0,0);
        cb[r] = cbox;
        ca[r] = (cbox.z - cbox.x + 1.0f) * (cbox.w - cbox.y + 1.0f);
        __syncthreads();
        if (i < TOPN) {
            float4 rb = topk[(size_t)b*MROWS + i];
            float rarea = (rb.z - rb.x + 1.0f) * (rb.w - rb.y + 1.0f);
            for (int q = 0; q < 64; ++q) {
                float4 cc = cb[q];
                float iw = fminf(rb.z, cc.z) - fmaxf(rb.x, cc.x) + 1.0f;
                float ih = fminf(rb.w, cc.w) - fmaxf(rb.y, cc.y) + 1.0f;
                iw = fmaxf(iw, 0.0f); ih = fmaxf(ih, 0.0f);
                float inter = iw * ih;
                float uni = (rarea + ca[q]) - inter;
                float iou = inter / uni;       // IEEE fp32 division, like numpy
                if (iou > 0.7f) word |= (1ULL << q);
            }
            int nvalid = TOPN - tj*64;
            if (nvalid < 64) word &= ((1ULL << nvalid) - 1ULL);
            if (ti == tj) {
                u64 cm = (r == 63) ? ~0ULL : ((1ULL << (r + 1)) - 1ULL);
                word &= ~cm;                   // enforce j > i
            }
        }
    }
    masksT[((size_t)(b*64 + tj))*RST + i] = word;
}

// ---------------- kernel 7: greedy scan (UNCHANGED from R12 — control) ----------------
#define NMS_PLOAD(cc) { \
    int cm = ((cc) > 62) ? 62 : (cc); \
    const u64* colp = mb + (size_t)cm*RST; \
    _Pragma("unroll") \
    for (int k = 0; k < NBLK; ++k) \
        if (k <= cm) pf[k] = colp[(size_t)k*64 + lane]; \
}

#define NMS_PSTORE(cc) { \
    int cm = ((cc) > 62) ? 62 : (cc); \
    int wmax = (cm < NBLK-1) ? cm+1 : NBLK; \
    _Pragma("unroll") \
    for (int k = 0; k < NBLK; ++k) \
        if (k < wmax) colbuf[k*64 + lane] = pf[k]; \
}

__global__ __launch_bounds__(64, 1) void k_nms(const u64* __restrict__ masksT,
                      const float4* __restrict__ topk,
                      float* __restrict__ out)
{
    int b = blockIdx.x;
    int lane = threadIdx.x;        // 0..63

    __shared__ u64 colbuf[NBLK*64];   // current column's history blocks
    __shared__ u32 kmexp[64][64];     // per-(chunk,row) keep select mask
    __shared__ u64 kmw[64];           // per-chunk keep bitmask (valid-masked)

    kmw[lane] = 0ull;
#pragma unroll
    for (int k = 0; k < 64; ++k) kmexp[k][lane] = 0u;

    {
        float* ob = out + (size_t)b*POSTN*5;
        for (int e = lane; e < POSTN*5; e += 64)
            ob[e] = ((e % 5) == 0) ? (float)b : 0.0f;
    }

    const u64* mb = masksT + (size_t)b*64*RST;

    u64 pf[NBLK];
    NMS_PLOAD(0)
    NMS_PSTORE(0)
    NMS_PLOAD(1)

    int kcnt = 0;
    for (int c = 0; c < 63; ++c) {
        u64 acc = 0;
        int kmax = (c < NBLK) ? c : NBLK;
#pragma unroll 8
        for (int k = 0; k < kmax; ++k) {
            u32 mk = kmexp[k][lane];
            u64 v = colbuf[k*64 + lane];
            acc |= v & (((u64)mk << 32) | mk);
        }
        for (int k = NBLK; k < c; ++k) {
            u32 mk = kmexp[k][lane];
            u64 v = mb[(size_t)c*RST + (size_t)k*64 + lane];
            acc |= v & (((u64)mk << 32) | mk);
        }
        u64 w = wave_or64_dpp(acc);
        u64 D = (c < NBLK) ? colbuf[c*64 + lane]
                           : mb[(size_t)c*RST + (size_t)c*64 + lane];
#pragma unroll
        for (int r = 0; r < 64; ++r) {
            u64 dr = readlane64(D, r);
            u64 t;
            asm("s_lshr_b64 %[t], %[w], %[rr]\n\t"
                "s_and_b64 %[t], %[t], 1\n\t"
                "s_cselect_b64 %[t], 0, %[d]\n\t"
                "s_or_b64 %[w], %[w], %[t]"
                : [w]"+s"(w), [t]"=&s"(t)
                : [d]"s"(dr), [rr]"i"(r)
                : "scc");
        }
        u64 kmask = ~w & ((c < 62) ? ~0ull : 0xFFFFFFFFull);
        kcnt += __popcll(kmask);
        if (lane == 0) kmw[c] = kmask;
        kmexp[c][lane] = ((u32)((kmask >> lane) & 1ull)) ? ~0u : 0u;

        if (kcnt >= POSTN || c == 62) break;
        NMS_PSTORE(c+1)
        NMS_PLOAD(c+2)
    }

    u64 keepw = kmw[lane];
    int cnt = __popcll(keepw);
    int pre = cnt;
    for (int d = 1; d < 64; d <<= 1) {
        int t = __shfl_up(pre, d);
        if (lane >= d) pre += t;
    }
    int excl = pre - cnt;
    asm volatile("s_waitcnt vmcnt(0)" ::: "memory");
    u64 wv = keepw; int rk = excl;
    while (wv) {
        int bpos = __ffsll((unsigned long long)wv) - 1;
        wv &= wv - 1;
        if (rk < POSTN) {
            int i = lane*64 + bpos;
            float4 bx = topk[(size_t)b*MROWS + i];
            float* o = out + ((size_t)b*POSTN + rk)*5;
            o[1] = bx.x; o[2] = bx.y; o[3] = bx.z; o[4] = bx.w;
        }
        ++rk;
    }
}

// ---------------- launch ----------------
extern "C" void kernel_launch(void* const* d_in, const int* in_sizes, int n_in,
                              void* d_out, int out_size, void* d_ws, size_t ws_size,
                              hipStream_t stream)
{
    const float* scores  = (const float*)d_in[0];
    const float* deltas  = (const float*)d_in[1];
    const float* im_info = (const float*)d_in[2];
    const float* vrange  = (const float*)d_in[3];
    float* out = (float*)d_out;

    char* ws = (char*)d_ws;
    size_t off = 0;
    auto alloc = [&](size_t bytes) -> void* {
        void* ptr = ws + off;
        off += (bytes + 255) & ~(size_t)255;
        return ptr;
    };
    u32*   fkeys   = (u32*)   alloc((size_t)NB*NPB*sizeof(u32));           // 2.36 MB
    u64*   cand    = (u64*)   alloc((size_t)NB*CANDCAP*sizeof(u64));       // 256 KB
    float4* topk   = (float4*)alloc((size_t)NB*MROWS*sizeof(float4));      // 256 KB
    u64*   masksT  = (u64*)   alloc((size_t)NB*64*RST*sizeof(u64));        // 8.52 MB
    u32*   bcnt    = (u32*)   alloc((size_t)NB*PBLK*sizeof(u32));          // 9 KB
    u32*   bbase   = (u32*)   alloc((size_t)NB*PBLK*sizeof(u32));          // 9 KB
    // zeroed region (single memset): coarseH | fineH | done counters
    u32*   coarseH = (u32*)   alloc((size_t)NREP*NB*256*sizeof(u32));      // 16 KB
    u32*   fineH   = (u32*)   alloc((size_t)NREP*NB*256*sizeof(u32));      // 16 KB
    u32*   dcnt    = (u32*)   alloc(256);                                  // done0..2
    // outputs written every run (no init needed)
    u32*   ccnt    = (u32*)   alloc(256);
    int*   cstar   = (int*)   alloc(256);
    u32*   cabove  = (u32*)   alloc(256);
    u32*   thresh16= (u32*)   alloc(256);

    Anchors A;
    gen_anchors(A.v);

    size_t zbytes = (char*)dcnt + 256 - (char*)coarseH;
    hipMemsetAsync(coarseH, 0, zbytes, stream);

    int total = NB*NPB;
    int blocks = (total + 255)/256;    // 2304, exact (NPB % 256 == 0)
    k_props<<<blocks, 256, 0, stream>>>(scores, deltas, im_info, vrange, A,
                                        fkeys, coarseH, cstar, cabove, &dcnt[0]);
    k_fineHist<<<blocks, 256, 0, stream>>>(fkeys, cstar, cabove, fineH, thresh16, &dcnt[1]);
    k_count<<<blocks, 256, 0, stream>>>(fkeys, thresh16, bcnt, bbase, ccnt, &dcnt[2]);
    k_emit<<<blocks, 256, 0, stream>>>(fkeys, thresh16, bbase, cand);
    dim3 rgrid(CANDCAP/64, NB);
    k_rank2<<<rgrid, 256, 0, stream>>>(cand, ccnt, deltas, im_info, A, topk);
    dim3 mgrid(TRI, NB);
    k_mask<<<mgrid, 64, 0, stream>>>(topk, masksT);
    k_nms<<<NB, 64, 0, stream>>>(masksT, topk, out);
}

// Round 15
// 143.479 us; speedup vs baseline: 3.8168x; 3.8168x over previous
//
#include <hip/hip_runtime.h>
#include <cmath>

// ---- problem constants ----
#define WD 128
#define HT 128
#define HW 16384            // H*W
#define NB 4
#define NA 9
#define NPB (NA*HW)         // anchors per batch = 147456
#define TOPN 4000
#define POSTN 1000
#define CANDCAP 8192        // max candidates per batch (fine-bin overshoot << this)
#define MROWS 4096          // padded rows for topk buffer
#define RST 4160            // row stride (u64s) per (b,word) mask stream
#define NTILE 63            // ceil(4000/64)
#define TRI (NTILE*(NTILE+1)/2)   // 2016 upper-triangle tiles
#define NREP 4              // histogram replicas (contention divider)
#define PBLK 576            // 256-thread blocks per batch (NPB/256)
#define NBLK 42             // LDS-staged column blocks (covers exit <= chunk 42)

typedef unsigned long long u64;
typedef unsigned int u32;

struct Anchors { float v[36]; };

// ---------------- host: replicate numpy _generate_anchors exactly ----------------
static void gen_anchors(float* out) {
    double base[4] = {0.0, 0.0, 15.0, 15.0};
    const double ratios[3] = {0.5, 1.0, 2.0};
    const double scales[3] = {8.0, 16.0, 32.0};
    double w = base[2] - base[0] + 1.0;
    double h = base[3] - base[1] + 1.0;
    double xc = base[0] + 0.5 * (w - 1.0);
    double yc = base[1] + 0.5 * (h - 1.0);
    double size = w * h;
    double ra[3][4];
    for (int r = 0; r < 3; ++r) {
        double ws = nearbyint(sqrt(size / ratios[r]));   // np.round = half-even
        double hs = nearbyint(ws * ratios[r]);
        ra[r][0] = xc - 0.5 * (ws - 1.0);
        ra[r][1] = yc - 0.5 * (hs - 1.0);
        ra[r][2] = xc + 0.5 * (ws - 1.0);
        ra[r][3] = yc + 0.5 * (hs - 1.0);
    }
    int k = 0;
    for (int r = 0; r < 3; ++r) {
        double w2 = ra[r][2] - ra[r][0] + 1.0;
        double h2 = ra[r][3] - ra[r][1] + 1.0;
        double x2c = ra[r][0] + 0.5 * (w2 - 1.0);
        double y2c = ra[r][1] + 0.5 * (h2 - 1.0);
        for (int s = 0; s < 3; ++s) {
            double ws = w2 * scales[s], hs = h2 * scales[s];
            out[k*4+0] = (float)(x2c - 0.5 * (ws - 1.0));
            out[k*4+1] = (float)(y2c - 0.5 * (hs - 1.0));
            out[k*4+2] = (float)(x2c + 0.5 * (ws - 1.0));
            out[k*4+3] = (float)(y2c + 0.5 * (hs - 1.0));
            ++k;
        }
    }
}

__device__ __forceinline__ u32 sortable_key(float sc) {
    u32 sb = __float_as_uint(sc);
    return sb ^ ((sb & 0x80000000u) ? 0xFFFFFFFFu : 0x80000000u);
}

__device__ __forceinline__ u64 readlane64(u64 v, int l) {
    u32 lo = (u32)__builtin_amdgcn_readlane((int)(u32)v, l);
    u32 hi = (u32)__builtin_amdgcn_readlane((int)(u32)(v >> 32), l);
    return ((u64)hi << 32) | lo;
}

// 64-lane OR-reduce on the VALU pipe via DPP (rocPRIM pattern).
__device__ __forceinline__ u64 wave_or64_dpp(u64 v) {
    u32 lo = (u32)v, hi = (u32)(v >> 32);
#define DPPOR(x, ctrl) x |= (u32)__builtin_amdgcn_update_dpp(0, (int)(x), ctrl, 0xf, 0xf, false)
    DPPOR(lo, 0x111); DPPOR(lo, 0x112); DPPOR(lo, 0x114); DPPOR(lo, 0x118);
    DPPOR(lo, 0x142); DPPOR(lo, 0x143);
    DPPOR(hi, 0x111); DPPOR(hi, 0x112); DPPOR(hi, 0x114); DPPOR(hi, 0x118);
    DPPOR(hi, 0x142); DPPOR(hi, 0x143);
#undef DPPOR
    u32 rlo = (u32)__builtin_amdgcn_readlane((int)lo, 63);
    u32 rhi = (u32)__builtin_amdgcn_readlane((int)hi, 63);
    return ((u64)rhi << 32) | rlo;
}

// Shared decode: used by k_props (filter) and k_rank2 (winner gather).
// Same source + contract(off) in both -> bit-identical boxes.
__device__ __forceinline__ float4 decode_box(const float* __restrict__ deltas,
                                             const float* __restrict__ im_info,
                                             const Anchors& A, int b, int a, int p)
{
#pragma clang fp contract(off)
    int hh = p >> 7;        // / W
    int ww = p & 127;       // % W
    float sx = (float)(ww * 16);
    float sy = (float)(hh * 16);
    float ax1 = A.v[a*4+0] + sx;
    float ay1 = A.v[a*4+1] + sy;
    float ax2 = A.v[a*4+2] + sx;
    float ay2 = A.v[a*4+3] + sy;
    const float* dbase = deltas + ((size_t)(b*36 + a*4))*HW + p;
    float dx = dbase[0];
    float dy = dbase[HW];
    float dw = dbase[2*HW];
    float dh = dbase[3*HW];
    float aw = ax2 - ax1 + 1.0f;
    float ah = ay2 - ay1 + 1.0f;
    float cx = ax1 + 0.5f*aw;
    float cy = ay1 + 0.5f*ah;
    float pcx = dx*aw + cx;
    float pcy = dy*ah + cy;
    float ew = (float)exp((double)dw);   // correctly-rounded f32 exp
    float eh = (float)exp((double)dh);
    float pw = ew * aw;
    float ph = eh * ah;
    float x1 = pcx - 0.5f*pw;
    float y1 = pcy - 0.5f*ph;
    float x2 = pcx + 0.5f*pw;
    float y2 = pcy + 0.5f*ph;
    float hmax = im_info[b*3+0] - 1.0f;
    float wmax = im_info[b*3+1] - 1.0f;
    x1 = fmaxf(x1, 0.0f); y1 = fmaxf(y1, 0.0f);
    x2 = fmaxf(x2, 0.0f); y2 = fmaxf(y2, 0.0f);
    x1 = fminf(x1, wmax); y1 = fminf(y1, hmax);
    x2 = fminf(x2, wmax); y2 = fminf(y2, hmax);
    return make_float4(x1, y1, x2, y2);
}

// ---------------- kernel 1: decode + filter + key store + coarse hist ----------------
__global__ void k_props(const float* __restrict__ scores,
                        const float* __restrict__ deltas,
                        const float* __restrict__ im_info,
                        const float* __restrict__ valid_range,
                        Anchors A,
                        u32* __restrict__ fkeys,
                        u32* __restrict__ coarseH)   // [NREP][NB][256]
{
#pragma clang fp contract(off)
    __shared__ u32 lh[256];
    int tid = threadIdx.x;
    lh[tid] = 0;
    __syncthreads();

    int n = blockIdx.x * 256 + tid;
    int b = n / NPB;
    int r = n - b*NPB;
    int a = r / HW;
    int p = r - a*HW;

    float4 bx = decode_box(deltas, im_info, A, b, a, p);
    float sc = scores[((size_t)(b*18 + 9 + a))*HW + p];
    float area = (bx.z - bx.x) * (bx.w - bx.y);
    float v0 = valid_range[b*2+0], v1 = valid_range[b*2+1];
    if (area < v0*v0 || area > v1*v1) sc = -1.0f;

    u32 key = sortable_key(sc);
    fkeys[n] = key;
    atomicAdd(&lh[key >> 24], 1u);
    __syncthreads();

    u32 v = lh[tid];
    if (v) {
        int rep = blockIdx.x & (NREP-1);
        atomicAdd(&coarseH[((size_t)rep*NB + b)*256 + tid], v);
    }
}

// ---------------- kernel 2: coarse threshold bin (parallel suffix-scan) ----------------
__global__ void k_findA(const u32* __restrict__ coarseH,
                        int* __restrict__ cstar, u32* __restrict__ cabove)
{
    __shared__ u32 sfx[256];
    int b = blockIdx.x, t = threadIdx.x;
    u32 s = 0;
    for (int rr = 0; rr < NREP; ++rr) s += coarseH[((size_t)rr*NB + b)*256 + t];
    sfx[t] = s;
    __syncthreads();
    for (int d = 1; d < 256; d <<= 1) {
        u32 add = (t + d < 256) ? sfx[t + d] : 0u;
        __syncthreads();
        sfx[t] += add;
        __syncthreads();
    }
    u32 mine = sfx[t];
    u32 nxt  = (t < 255) ? sfx[t+1] : 0u;
    if (mine >= TOPN && (t == 255 || nxt < TOPN)) { cstar[b] = t; cabove[b] = nxt; }
}

// ---------------- kernel 3: fine histogram (bits 23:16) within coarse bin c* ----------------
__global__ void k_fineHist(const u32* __restrict__ fkeys,
                           const int* __restrict__ cstar,
                           u32* __restrict__ fineH)   // [NREP][NB][256]
{
    int n = blockIdx.x * 256 + threadIdx.x;
    int b = n / NPB;
    u32 key = fkeys[n];
    if ((int)(key >> 24) == cstar[b]) {
        int rep = blockIdx.x & (NREP-1);
        atomicAdd(&fineH[((size_t)rep*NB + b)*256 + ((key >> 16) & 255u)], 1u);
    }
}

// ---------------- kernel 4: exact 16-bit threshold (parallel suffix-scan) ----------------
__global__ void k_findB(const u32* __restrict__ fineH,
                        const int* __restrict__ cstar, const u32* __restrict__ cabove,
                        u32* __restrict__ thresh16)
{
    __shared__ u32 sfx[256];
    int b = blockIdx.x, t = threadIdx.x;
    u32 s = 0;
    for (int rr = 0; rr < NREP; ++rr) s += fineH[((size_t)rr*NB + b)*256 + t];
    sfx[t] = s;
    __syncthreads();
    for (int d = 1; d < 256; d <<= 1) {
        u32 add = (t + d < 256) ? sfx[t + d] : 0u;
        __syncthreads();
        sfx[t] += add;
        __syncthreads();
    }
    u32 ca   = cabove[b];
    u32 mine = ca + sfx[t];
    u32 nxt  = (t < 255) ? (ca + sfx[t+1]) : ca;
    if (mine >= TOPN && (t == 255 || nxt < TOPN))
        thresh16[b] = ((u32)cstar[b] << 8) | (u32)t;
}

// ---------------- kernel 5a: per-block candidate counts (no atomics) ----------------
__global__ void k_count(const u32* __restrict__ fkeys,
                        const u32* __restrict__ thresh16,
                        u32* __restrict__ bcnt)
{
    int n = blockIdx.x * 256 + threadIdx.x;
    int b = n / NPB;
    bool cond = (fkeys[n] >> 16) >= thresh16[b];
    u64 m = __ballot(cond);
    __shared__ u32 wc[4];
    int wave = threadIdx.x >> 6;
    if ((threadIdx.x & 63) == 0) wc[wave] = (u32)__popcll(m);
    __syncthreads();
    if (threadIdx.x == 0) bcnt[blockIdx.x] = wc[0] + wc[1] + wc[2] + wc[3];
}

// ---------------- kernel 5b: per-batch exclusive scan of block counts ----------------
__global__ void k_scanblk(const u32* __restrict__ bcnt,
                          u32* __restrict__ bbase, u32* __restrict__ ccnt)
{
    __shared__ u32 s[PBLK];
    int b = blockIdx.x, t = threadIdx.x;      // PBLK threads
    u32 v = bcnt[b*PBLK + t];
    s[t] = v;
    __syncthreads();
    for (int d = 1; d < PBLK; d <<= 1) {
        u32 add = (t >= d) ? s[t-d] : 0;
        __syncthreads();
        s[t] += add;
        __syncthreads();
    }
    bbase[b*PBLK + t] = s[t] - v;             // exclusive prefix
    if (t == PBLK-1) ccnt[b] = s[t];          // per-batch total (plain store)
}

// ---------------- kernel 5c: emit candidates at deterministic positions ----------------
__global__ void k_emit(const u32* __restrict__ fkeys,
                       const u32* __restrict__ thresh16,
                       const u32* __restrict__ bbase,
                       u64* __restrict__ cand)
{
    int n = blockIdx.x * 256 + threadIdx.x;
    int b = n / NPB;
    int r = n - b*NPB;
    int a = r / HW;
    int p = r - a*HW;
    u32 key = fkeys[n];
    bool cond = (key >> 16) >= thresh16[b];
    u64 m = __ballot(cond);
    int lane = threadIdx.x & 63;
    int wave = threadIdx.x >> 6;
    __shared__ u32 wb[4];
    if (lane == 0) wb[wave] = (u32)__popcll(m);
    __syncthreads();
    if (cond) {
        u32 wbase = 0;
        for (int wv = 0; wv < wave; ++wv) wbase += wb[wv];
        u32 off = (u32)__popcll(m & ((1ull << lane) - 1ull));
        u32 pos = bbase[blockIdx.x] + wbase + off;
        if (pos < CANDCAP) {
            u32 t = (u32)(p*NA + a);               // reference flat index
            cand[(size_t)b*CANDCAP + pos] = ((u64)key << 32) | (u32)(~t);
        }
    }
}

// ---------------- kernel 6: global rank-sort in LDS + winner re-decode ----------------
// Inner scan UNROLLED x16: 16 independent ds_read_b64 in flight per step.
__global__ void k_rank2(const u64* __restrict__ cand, const u32* __restrict__ ccnt,
                        const float* __restrict__ deltas,
                        const float* __restrict__ im_info,
                        Anchors A,
                        float4* __restrict__ topk)
{
    __shared__ u64 kk[CANDCAP];   // 64 KB
    __shared__ u32 ps[256];
    int b = blockIdx.y;
    u32 N = ccnt[b]; if (N > CANDCAP) N = CANDCAP;
    int tid = threadIdx.x;
    if ((u32)(blockIdx.x * 64) >= N) return;    // whole block idle
    for (u32 i = tid; i < N; i += 256) kk[i] = cand[(size_t)b*CANDCAP + i];
    __syncthreads();
    int kl = tid & 63, seg = tid >> 6;
    u32 ki = (u32)(blockIdx.x * 64 + kl);
    u64 mykey = (ki < N) ? kk[ki] : ~0ull;
    u32 segN = (N + 3) >> 2;
    u32 s0 = seg * segN;
    u32 s1 = s0 + segN; if (s1 > N) s1 = N;
    u32 pr = 0;
    u32 i = s0;
    for (; i + 16 <= s1; i += 16) {
        u64 v0 = kk[i+0],  v1 = kk[i+1],  v2 = kk[i+2],  v3 = kk[i+3];
        u64 v4 = kk[i+4],  v5 = kk[i+5],  v6 = kk[i+6],  v7 = kk[i+7];
        u64 v8 = kk[i+8],  v9 = kk[i+9],  va = kk[i+10], vb = kk[i+11];
        u64 vc = kk[i+12], vd = kk[i+13], ve = kk[i+14], vf = kk[i+15];
        pr += (v0 > mykey) + (v1 > mykey) + (v2 > mykey) + (v3 > mykey);
        pr += (v4 > mykey) + (v5 > mykey) + (v6 > mykey) + (v7 > mykey);
        pr += (v8 > mykey) + (v9 > mykey) + (va > mykey) + (vb > mykey);
        pr += (vc > mykey) + (vd > mykey) + (ve > mykey) + (vf > mykey);
    }
    for (; i < s1; ++i) pr += (kk[i] > mykey) ? 1u : 0u;
    ps[tid] = pr;
    __syncthreads();
    if (seg == 0 && ki < N) {
        u32 rank = ps[kl] + ps[kl+64] + ps[kl+128] + ps[kl+192];
        if (rank < TOPN) {
            u32 t = ~((u32)mykey);
            int a = (int)(t % 9u);
            int p = (int)(t / 9u);
            topk[(size_t)b*MROWS + rank] = decode_box(deltas, im_info, A, b, a, p);
        }
    }
}

// ---------------- kernel 7: suppression-mask tiles — UPPER TRIANGLE ONLY ----------------
// k_nms reads only tj >= ti blocks (column pull: blocks k<=c of column c).
__global__ void k_mask(const float4* __restrict__ topk, u64* __restrict__ masksT)
{
#pragma clang fp contract(off)
    int L = blockIdx.x;            // 0..TRI-1
    int b = blockIdx.y;
    int ti = (int)((2.0*NTILE + 1.0 -
                    sqrt((2.0*NTILE + 1.0)*(2.0*NTILE + 1.0) - 8.0*(double)L)) * 0.5);
    while ((ti+1)*NTILE - ((ti+1)*ti)/2 <= L) ++ti;          // fixup sqrt rounding
    while (ti*NTILE - (ti*(ti-1))/2 > L) --ti;
    int tj = ti + (L - (ti*NTILE - (ti*(ti-1))/2));

    int r = threadIdx.x;           // 0..63
    int i = ti*64 + r;
    __shared__ float4 cb[64];
    __shared__ float  ca[64];
    u64 word = 0;
    {
        int jj = tj*64 + r;
        float4 cbox = (jj < TOPN) ? topk[(size_t)b*MROWS + jj] : make_float4(0,0,0,0);
        cb[r] = cbox;
        ca[r] = (cbox.z - cbox.x + 1.0f) * (cbox.w - cbox.y + 1.0f);
        __syncthreads();
        if (i < TOPN) {
            float4 rb = topk[(size_t)b*MROWS + i];
            float rarea = (rb.z - rb.x + 1.0f) * (rb.w - rb.y + 1.0f);
            for (int q = 0; q < 64; ++q) {
                float4 cc = cb[q];
                float iw = fminf(rb.z, cc.z) - fmaxf(rb.x, cc.x) + 1.0f;
                float ih = fminf(rb.w, cc.w) - fmaxf(rb.y, cc.y) + 1.0f;
                iw = fmaxf(iw, 0.0f); ih = fmaxf(ih, 0.0f);
                float inter = iw * ih;
                float uni = (rarea + ca[q]) - inter;
                float iou = inter / uni;       // IEEE fp32 division, like numpy
                if (iou > 0.7f) word |= (1ULL << q);
            }
            int nvalid = TOPN - tj*64;
            if (nvalid < 64) word &= ((1ULL << nvalid) - 1ULL);
            if (ti == tj) {
                u64 cm = (r == 63) ? ~0ULL : ((1ULL << (r + 1)) - 1ULL);
                word &= ~cm;                   // enforce j > i
            }
        }
    }
    masksT[((size_t)(b*64 + tj))*RST + i] = word;
}

// ---------------- kernel 8: greedy scan (UNCHANGED R12 control) ----------------
#define NMS_PLOAD(cc) { \
    int cm = ((cc) > 62) ? 62 : (cc); \
    const u64* colp = mb + (size_t)cm*RST; \
    _Pragma("unroll") \
    for (int k = 0; k < NBLK; ++k) \
        if (k <= cm) pf[k] = colp[(size_t)k*64 + lane]; \
}

#define NMS_PSTORE(cc) { \
    int cm = ((cc) > 62) ? 62 : (cc); \
    int wmax = (cm < NBLK-1) ? cm+1 : NBLK; \
    _Pragma("unroll") \
    for (int k = 0; k < NBLK; ++k) \
        if (k < wmax) colbuf[k*64 + lane] = pf[k]; \
}

__global__ __launch_bounds__(64, 1) void k_nms(const u64* __restrict__ masksT,
                      const float4* __restrict__ topk,
                      float* __restrict__ out)
{
    int b = blockIdx.x;
    int lane = threadIdx.x;        // 0..63

    __shared__ u64 colbuf[NBLK*64];   // current column's history blocks
    __shared__ u32 kmexp[64][64];     // per-(chunk,row) keep select mask
    __shared__ u64 kmw[64];           // per-chunk keep bitmask (valid-masked)

    kmw[lane] = 0ull;
#pragma unroll
    for (int k = 0; k < 64; ++k) kmexp[k][lane] = 0u;

    {
        float* ob = out + (size_t)b*POSTN*5;
        for (int e = lane; e < POSTN*5; e += 64)
            ob[e] = ((e % 5) == 0) ? (float)b : 0.0f;
    }

    const u64* mb = masksT + (size_t)b*64*RST;

    u64 pf[NBLK];
    NMS_PLOAD(0)
    NMS_PSTORE(0)
    NMS_PLOAD(1)

    int kcnt = 0;
    for (int c = 0; c < 63; ++c) {
        u64 acc = 0;
        int kmax = (c < NBLK) ? c : NBLK;
#pragma unroll 8
        for (int k = 0; k < kmax; ++k) {
            u32 mk = kmexp[k][lane];
            u64 v = colbuf[k*64 + lane];
            acc |= v & (((u64)mk << 32) | mk);
        }
        for (int k = NBLK; k < c; ++k) {
            u32 mk = kmexp[k][lane];
            u64 v = mb[(size_t)c*RST + (size_t)k*64 + lane];
            acc |= v & (((u64)mk << 32) | mk);
        }
        u64 w = wave_or64_dpp(acc);
        u64 D = (c < NBLK) ? colbuf[c*64 + lane]
                           : mb[(size_t)c*RST + (size_t)c*64 + lane];
#pragma unroll
        for (int r = 0; r < 64; ++r) {
            u64 dr = readlane64(D, r);
            u64 t;
            asm("s_lshr_b64 %[t], %[w], %[rr]\n\t"
                "s_and_b64 %[t], %[t], 1\n\t"
                "s_cselect_b64 %[t], 0, %[d]\n\t"
                "s_or_b64 %[w], %[w], %[t]"
                : [w]"+s"(w), [t]"=&s"(t)
                : [d]"s"(dr), [rr]"i"(r)
                : "scc");
        }
        u64 kmask = ~w & ((c < 62) ? ~0ull : 0xFFFFFFFFull);
        kcnt += __popcll(kmask);
        if (lane == 0) kmw[c] = kmask;
        kmexp[c][lane] = ((u32)((kmask >> lane) & 1ull)) ? ~0u : 0u;

        if (kcnt >= POSTN || c == 62) break;
        NMS_PSTORE(c+1)
        NMS_PLOAD(c+2)
    }

    u64 keepw = kmw[lane];
    int cnt = __popcll(keepw);
    int pre = cnt;
    for (int d = 1; d < 64; d <<= 1) {
        int t = __shfl_up(pre, d);
        if (lane >= d) pre += t;
    }
    int excl = pre - cnt;
    asm volatile("s_waitcnt vmcnt(0)" ::: "memory");
    u64 wv = keepw; int rk = excl;
    while (wv) {
        int bpos = __ffsll((unsigned long long)wv) - 1;
        wv &= wv - 1;
        if (rk < POSTN) {
            int i = lane*64 + bpos;
            float4 bx = topk[(size_t)b*MROWS + i];
            float* o = out + ((size_t)b*POSTN + rk)*5;
            o[1] = bx.x; o[2] = bx.y; o[3] = bx.z; o[4] = bx.w;
        }
        ++rk;
    }
}

// ---------------- launch ----------------
extern "C" void kernel_launch(void* const* d_in, const int* in_sizes, int n_in,
                              void* d_out, int out_size, void* d_ws, size_t ws_size,
                              hipStream_t stream)
{
    const float* scores  = (const float*)d_in[0];
    const float* deltas  = (const float*)d_in[1];
    const float* im_info = (const float*)d_in[2];
    const float* vrange  = (const float*)d_in[3];
    float* out = (float*)d_out;

    char* ws = (char*)d_ws;
    size_t off = 0;
    auto alloc = [&](size_t bytes) -> void* {
        void* ptr = ws + off;
        off += (bytes + 255) & ~(size_t)255;
        return ptr;
    };
    u32*   fkeys   = (u32*)   alloc((size_t)NB*NPB*sizeof(u32));           // 2.36 MB
    u64*   cand    = (u64*)   alloc((size_t)NB*CANDCAP*sizeof(u64));       // 256 KB
    float4* topk   = (float4*)alloc((size_t)NB*MROWS*sizeof(float4));      // 256 KB
    u64*   masksT  = (u64*)   alloc((size_t)NB*64*RST*sizeof(u64));        // 8.52 MB
    u32*   bcnt    = (u32*)   alloc((size_t)NB*PBLK*sizeof(u32));          // 9 KB
    u32*   bbase   = (u32*)   alloc((size_t)NB*PBLK*sizeof(u32));          // 9 KB
    // zeroed region (single memset): coarseH | fineH
    u32*   coarseH = (u32*)   alloc((size_t)NREP*NB*256*sizeof(u32));      // 16 KB
    u32*   fineH   = (u32*)   alloc((size_t)NREP*NB*256*sizeof(u32));      // 16 KB
    // outputs written every run (no init needed)
    u32*   ccnt    = (u32*)   alloc(256);
    int*   cstar   = (int*)   alloc(256);
    u32*   cabove  = (u32*)   alloc(256);
    u32*   thresh16= (u32*)   alloc(256);

    Anchors A;
    gen_anchors(A.v);

    size_t zbytes = (char*)fineH + (size_t)NREP*NB*256*sizeof(u32) - (char*)coarseH;
    hipMemsetAsync(coarseH, 0, zbytes, stream);

    int total = NB*NPB;
    int blocks = (total + 255)/256;    // 2304, exact (NPB % 256 == 0)
    k_props<<<blocks, 256, 0, stream>>>(scores, deltas, im_info, vrange, A, fkeys, coarseH);
    k_findA<<<NB, 256, 0, stream>>>(coarseH, cstar, cabove);
    k_fineHist<<<blocks, 256, 0, stream>>>(fkeys, cstar, fineH);
    k_findB<<<NB, 256, 0, stream>>>(fineH, cstar, cabove, thresh16);
    k_count<<<blocks, 256, 0, stream>>>(fkeys, thresh16, bcnt);
    k_scanblk<<<NB, PBLK, 0, stream>>>(bcnt, bbase, ccnt);
    k_emit<<<blocks, 256, 0, stream>>>(fkeys, thresh16, bbase, cand);
    dim3 rgrid(CANDCAP/64, NB);
    k_rank2<<<rgrid, 256, 0, stream>>>(cand, ccnt, deltas, im_info, A, topk);
    dim3 mgrid(TRI, NB);
    k_mask<<<mgrid, 64, 0, stream>>>(topk, masksT);
    k_nms<<<NB, 64, 0, stream>>>(masksT, topk, out);
}

// Round 16
// 134.270 us; speedup vs baseline: 4.0786x; 1.0686x over previous
//
#include <hip/hip_runtime.h>
#include <cmath>

// ---- problem constants ----
#define WD 128
#define HT 128
#define HW 16384            // H*W
#define NB 4
#define NA 9
#define NPB (NA*HW)         // anchors per batch = 147456
#define TOPN 4000
#define POSTN 1000
#define CANDCAP 8192        // max candidates staged in rank2 LDS
#define REPCAP 1024         // per-replica candidate region
#define NREPL 32            // emit counter replicas per batch
#define MROWS 4096          // padded rows for topk buffer
#define RST 4160            // row stride (u64s) per (b,word) mask stream
#define NTILE 63            // ceil(4000/64)
#define TRI (NTILE*(NTILE+1)/2)   // 2016 upper-triangle tiles
#define NREP 4              // histogram replicas (contention divider)
#define PBLK 576            // 256-thread blocks per batch (NPB/256)
#define NBINS 4096          // 12-bit histogram
#define NBLK 42             // LDS-staged column blocks (covers exit <= chunk 42)

typedef unsigned long long u64;
typedef unsigned int u32;

struct Anchors { float v[36]; };

// ---------------- host: replicate numpy _generate_anchors exactly ----------------
static void gen_anchors(float* out) {
    double base[4] = {0.0, 0.0, 15.0, 15.0};
    const double ratios[3] = {0.5, 1.0, 2.0};
    const double scales[3] = {8.0, 16.0, 32.0};
    double w = base[2] - base[0] + 1.0;
    double h = base[3] - base[1] + 1.0;
    double xc = base[0] + 0.5 * (w - 1.0);
    double yc = base[1] + 0.5 * (h - 1.0);
    double size = w * h;
    double ra[3][4];
    for (int r = 0; r < 3; ++r) {
        double ws = nearbyint(sqrt(size / ratios[r]));   // np.round = half-even
        double hs = nearbyint(ws * ratios[r]);
        ra[r][0] = xc - 0.5 * (ws - 1.0);
        ra[r][1] = yc - 0.5 * (hs - 1.0);
        ra[r][2] = xc + 0.5 * (ws - 1.0);
        ra[r][3] = yc + 0.5 * (hs - 1.0);
    }
    int k = 0;
    for (int r = 0; r < 3; ++r) {
        double w2 = ra[r][2] - ra[r][0] + 1.0;
        double h2 = ra[r][3] - ra[r][1] + 1.0;
        double x2c = ra[r][0] + 0.5 * (w2 - 1.0);
        double y2c = ra[r][1] + 0.5 * (h2 - 1.0);
        for (int s = 0; s < 3; ++s) {
            double ws = w2 * scales[s], hs = h2 * scales[s];
            out[k*4+0] = (float)(x2c - 0.5 * (ws - 1.0));
            out[k*4+1] = (float)(y2c - 0.5 * (hs - 1.0));
            out[k*4+2] = (float)(x2c + 0.5 * (ws - 1.0));
            out[k*4+3] = (float)(y2c + 0.5 * (hs - 1.0));
            ++k;
        }
    }
}

__device__ __forceinline__ u32 sortable_key(float sc) {
    u32 sb = __float_as_uint(sc);
    return sb ^ ((sb & 0x80000000u) ? 0xFFFFFFFFu : 0x80000000u);
}

__device__ __forceinline__ u64 readlane64(u64 v, int l) {
    u32 lo = (u32)__builtin_amdgcn_readlane((int)(u32)v, l);
    u32 hi = (u32)__builtin_amdgcn_readlane((int)(u32)(v >> 32), l);
    return ((u64)hi << 32) | lo;
}

// 64-lane OR-reduce on the VALU pipe via DPP (rocPRIM pattern).
__device__ __forceinline__ u64 wave_or64_dpp(u64 v) {
    u32 lo = (u32)v, hi = (u32)(v >> 32);
#define DPPOR(x, ctrl) x |= (u32)__builtin_amdgcn_update_dpp(0, (int)(x), ctrl, 0xf, 0xf, false)
    DPPOR(lo, 0x111); DPPOR(lo, 0x112); DPPOR(lo, 0x114); DPPOR(lo, 0x118);
    DPPOR(lo, 0x142); DPPOR(lo, 0x143);
    DPPOR(hi, 0x111); DPPOR(hi, 0x112); DPPOR(hi, 0x114); DPPOR(hi, 0x118);
    DPPOR(hi, 0x142); DPPOR(hi, 0x143);
#undef DPPOR
    u32 rlo = (u32)__builtin_amdgcn_readlane((int)lo, 63);
    u32 rhi = (u32)__builtin_amdgcn_readlane((int)hi, 63);
    return ((u64)rhi << 32) | rlo;
}

// Shared decode: used by k_props (filter) and k_rank2 (winner gather).
// Same source + contract(off) in both -> bit-identical boxes.
__device__ __forceinline__ float4 decode_box(const float* __restrict__ deltas,
                                             const float* __restrict__ im_info,
                                             const Anchors& A, int b, int a, int p)
{
#pragma clang fp contract(off)
    int hh = p >> 7;        // / W
    int ww = p & 127;       // % W
    float sx = (float)(ww * 16);
    float sy = (float)(hh * 16);
    float ax1 = A.v[a*4+0] + sx;
    float ay1 = A.v[a*4+1] + sy;
    float ax2 = A.v[a*4+2] + sx;
    float ay2 = A.v[a*4+3] + sy;
    const float* dbase = deltas + ((size_t)(b*36 + a*4))*HW + p;
    float dx = dbase[0];
    float dy = dbase[HW];
    float dw = dbase[2*HW];
    float dh = dbase[3*HW];
    float aw = ax2 - ax1 + 1.0f;
    float ah = ay2 - ay1 + 1.0f;
    float cx = ax1 + 0.5f*aw;
    float cy = ay1 + 0.5f*ah;
    float pcx = dx*aw + cx;
    float pcy = dy*ah + cy;
    float ew = (float)exp((double)dw);   // correctly-rounded f32 exp
    float eh = (float)exp((double)dh);
    float pw = ew * aw;
    float ph = eh * ah;
    float x1 = pcx - 0.5f*pw;
    float y1 = pcy - 0.5f*ph;
    float x2 = pcx + 0.5f*pw;
    float y2 = pcy + 0.5f*ph;
    float hmax = im_info[b*3+0] - 1.0f;
    float wmax = im_info[b*3+1] - 1.0f;
    x1 = fmaxf(x1, 0.0f); y1 = fmaxf(y1, 0.0f);
    x2 = fmaxf(x2, 0.0f); y2 = fmaxf(y2, 0.0f);
    x1 = fminf(x1, wmax); y1 = fminf(y1, hmax);
    x2 = fminf(x2, wmax); y2 = fminf(y2, hmax);
    return make_float4(x1, y1, x2, y2);
}

// ---------------- kernel 1: decode + filter + key store + 12-bit LDS histogram ----------------
__global__ void k_props(const float* __restrict__ scores,
                        const float* __restrict__ deltas,
                        const float* __restrict__ im_info,
                        const float* __restrict__ valid_range,
                        Anchors A,
                        u32* __restrict__ fkeys,
                        u32* __restrict__ hist12)    // [NREP][NB][NBINS]
{
#pragma clang fp contract(off)
    __shared__ u32 lh[NBINS];   // 16 KB
    int tid = threadIdx.x;
#pragma unroll
    for (int i = 0; i < NBINS/256; ++i) lh[tid + i*256] = 0;
    __syncthreads();

    int n = blockIdx.x * 256 + tid;
    int b = n / NPB;
    int r = n - b*NPB;
    int a = r / HW;
    int p = r - a*HW;

    float4 bx = decode_box(deltas, im_info, A, b, a, p);
    float sc = scores[((size_t)(b*18 + 9 + a))*HW + p];
    float area = (bx.z - bx.x) * (bx.w - bx.y);
    float v0 = valid_range[b*2+0], v1 = valid_range[b*2+1];
    if (area < v0*v0 || area > v1*v1) sc = -1.0f;

    u32 key = sortable_key(sc);
    fkeys[n] = key;
    atomicAdd(&lh[key >> 20], 1u);
    __syncthreads();

    int rep = blockIdx.x & (NREP-1);
    u32* gh = hist12 + ((size_t)rep*NB + b)*NBINS;
#pragma unroll
    for (int i = 0; i < NBINS/256; ++i) {
        u32 v = lh[tid + i*256];
        if (v) atomicAdd(&gh[tid + i*256], v);
    }
}

// ---------------- kernel 2: 12-bit threshold via suffix-scan (1024 threads/batch) ----------------
__global__ void k_findT(const u32* __restrict__ hist12, u32* __restrict__ thresh12)
{
    __shared__ u32 sfx[1024];
    int b = blockIdx.x, t = threadIdx.x;    // 1024 threads; thread owns bins 4t..4t+3
    u32 bin0 = 0, bin1 = 0, bin2 = 0, bin3 = 0;
    for (int rr = 0; rr < NREP; ++rr) {
        const u32* h = hist12 + ((size_t)rr*NB + b)*NBINS + t*4;
        bin0 += h[0]; bin1 += h[1]; bin2 += h[2]; bin3 += h[3];
    }
    u32 s4 = bin0 + bin1 + bin2 + bin3;
    sfx[t] = s4;
    __syncthreads();
    for (int d = 1; d < 1024; d <<= 1) {
        u32 add = (t + d < 1024) ? sfx[t + d] : 0u;
        __syncthreads();
        sfx[t] += add;
        __syncthreads();
    }
    u32 above = (t < 1023) ? sfx[t+1] : 0u;     // sum of bins >= 4(t+1)
    u32 c3 = bin3 + above;
    u32 c2 = bin2 + c3;
    u32 c1 = bin1 + c2;
    u32 c0 = bin0 + c1;
    if (c3 >= TOPN && above < TOPN) thresh12[b] = (u32)(t*4 + 3);
    if (c2 >= TOPN && c3    < TOPN) thresh12[b] = (u32)(t*4 + 2);
    if (c1 >= TOPN && c2    < TOPN) thresh12[b] = (u32)(t*4 + 1);
    if (c0 >= TOPN && c1    < TOPN) thresh12[b] = (u32)(t*4 + 0);
}

// ---------------- kernel 3: emit candidates (replicated wave-aggregated counters) ----------------
// Order within cand is nondeterministic; k_rank2's rank-sort canonicalizes.
__global__ void k_emit(const u32* __restrict__ fkeys,
                       const u32* __restrict__ thresh12,
                       u32* __restrict__ ccntRep,     // [NB*NREPL] stride-16 u32 (64B lines)
                       u64* __restrict__ cand)        // [NB][NREPL][REPCAP]
{
    int tid = threadIdx.x;
    int n = blockIdx.x * 256 + tid;
    int b = n / NPB;
    int r = n - b*NPB;
    int a = r / HW;
    int p = r - a*HW;
    u32 key = fkeys[n];
    bool cond = (key >> 20) >= thresh12[b];
    u64 m = __ballot(cond);
    int lane = tid & 63;
    int rep = blockIdx.x & (NREPL-1);
    if (cond) {
        int leader = __ffsll((unsigned long long)m) - 1;
        u32 base = 0;
        if (lane == leader)
            base = atomicAdd(&ccntRep[(b*NREPL + rep)*16], (u32)__popcll(m));
        base = (u32)__shfl((int)base, leader);
        u32 pos = base + (u32)__popcll(m & ((1ull << lane) - 1ull));
        if (pos < REPCAP) {
            u32 t = (u32)(p*NA + a);               // reference flat index
            cand[((size_t)b*NREPL + rep)*REPCAP + pos] = ((u64)key << 32) | (u32)(~t);
        }
    }
}

// ---------------- kernel 4: region-compact + global rank-sort in LDS + winner re-decode ----------------
__global__ void k_rank2(const u64* __restrict__ cand, const u32* __restrict__ ccntRep,
                        const float* __restrict__ deltas,
                        const float* __restrict__ im_info,
                        Anchors A,
                        float4* __restrict__ topk)
{
    __shared__ u64 kk[CANDCAP];   // 64 KB
    __shared__ u32 ps[256];
    __shared__ u32 rcnt[32];
    __shared__ u32 roff[33];
    int b = blockIdx.y;
    int tid = threadIdx.x;
    if (tid < 32) {
        u32 c = ccntRep[(b*NREPL + tid)*16];
        rcnt[tid] = (c > REPCAP) ? REPCAP : c;
    }
    __syncthreads();
    if (tid == 0) {
        u32 acc = 0;
        for (int i = 0; i < 32; ++i) { roff[i] = acc; acc += rcnt[i]; }
        roff[32] = (acc > CANDCAP) ? CANDCAP : acc;
    }
    __syncthreads();
    u32 N = roff[32];
    if ((u32)(blockIdx.x * 64) >= N) return;    // whole block idle
    for (int rr = 0; rr < 32; ++rr) {
        u32 len = rcnt[rr], base = roff[rr];
        const u64* src = cand + ((size_t)b*NREPL + rr)*REPCAP;
        for (u32 i = tid; i < len; i += 256) {
            u32 g = base + i;
            if (g < CANDCAP) kk[g] = src[i];
        }
    }
    __syncthreads();
    int kl = tid & 63, seg = tid >> 6;
    u32 ki = (u32)(blockIdx.x * 64 + kl);
    u64 mykey = (ki < N) ? kk[ki] : ~0ull;
    u32 segN = (N + 3) >> 2;
    u32 s0 = seg * segN;
    u32 s1 = s0 + segN; if (s1 > N) s1 = N;
    u32 pr = 0;
    u32 i = s0;
    for (; i + 16 <= s1; i += 16) {
        u64 v0 = kk[i+0],  v1 = kk[i+1],  v2 = kk[i+2],  v3 = kk[i+3];
        u64 v4 = kk[i+4],  v5 = kk[i+5],  v6 = kk[i+6],  v7 = kk[i+7];
        u64 v8 = kk[i+8],  v9 = kk[i+9],  va = kk[i+10], vb = kk[i+11];
        u64 vc = kk[i+12], vd = kk[i+13], ve = kk[i+14], vf = kk[i+15];
        pr += (v0 > mykey) + (v1 > mykey) + (v2 > mykey) + (v3 > mykey);
        pr += (v4 > mykey) + (v5 > mykey) + (v6 > mykey) + (v7 > mykey);
        pr += (v8 > mykey) + (v9 > mykey) + (va > mykey) + (vb > mykey);
        pr += (vc > mykey) + (vd > mykey) + (ve > mykey) + (vf > mykey);
    }
    for (; i < s1; ++i) pr += (kk[i] > mykey) ? 1u : 0u;
    ps[tid] = pr;
    __syncthreads();
    if (seg == 0 && ki < N) {
        u32 rank = ps[kl] + ps[kl+64] + ps[kl+128] + ps[kl+192];
        if (rank < TOPN) {
            u32 t = ~((u32)mykey);
            int a = (int)(t % 9u);
            int p = (int)(t / 9u);
            topk[(size_t)b*MROWS + rank] = decode_box(deltas, im_info, A, b, a, p);
        }
    }
}

// ---------------- kernel 5: suppression-mask tiles — UPPER TRIANGLE ONLY ----------------
__global__ void k_mask(const float4* __restrict__ topk, u64* __restrict__ masksT)
{
#pragma clang fp contract(off)
    int L = blockIdx.x;            // 0..TRI-1
    int b = blockIdx.y;
    int ti = (int)((2.0*NTILE + 1.0 -
                    sqrt((2.0*NTILE + 1.0)*(2.0*NTILE + 1.0) - 8.0*(double)L)) * 0.5);
    while ((ti+1)*NTILE - ((ti+1)*ti)/2 <= L) ++ti;          // fixup sqrt rounding
    while (ti*NTILE - (ti*(ti-1))/2 > L) --ti;
    int tj = ti + (L - (ti*NTILE - (ti*(ti-1))/2));

    int r = threadIdx.x;           // 0..63
    int i = ti*64 + r;
    __shared__ float4 cb[64];
    __shared__ float  ca[64];
    u64 word = 0;
    {
        int jj = tj*64 + r;
        float4 cbox = (jj < TOPN) ? topk[(size_t)b*MROWS + jj] : make_float4(0,0,0,0);
        cb[r] = cbox;
        ca[r] = (cbox.z - cbox.x + 1.0f) * (cbox.w - cbox.y + 1.0f);
        __syncthreads();
        if (i < TOPN) {
            float4 rb = topk[(size_t)b*MROWS + i];
            float rarea = (rb.z - rb.x + 1.0f) * (rb.w - rb.y + 1.0f);
            for (int q = 0; q < 64; ++q) {
                float4 cc = cb[q];
                float iw = fminf(rb.z, cc.z) - fmaxf(rb.x, cc.x) + 1.0f;
                float ih = fminf(rb.w, cc.w) - fmaxf(rb.y, cc.y) + 1.0f;
                iw = fmaxf(iw, 0.0f); ih = fmaxf(ih, 0.0f);
                float inter = iw * ih;
                float uni = (rarea + ca[q]) - inter;
                float iou = inter / uni;       // IEEE fp32 division, like numpy
                if (iou > 0.7f) word |= (1ULL << q);
            }
            int nvalid = TOPN - tj*64;
            if (nvalid < 64) word &= ((1ULL << nvalid) - 1ULL);
            if (ti == tj) {
                u64 cm = (r == 63) ? ~0ULL : ((1ULL << (r + 1)) - 1ULL);
                word &= ~cm;                   // enforce j > i
            }
        }
    }
    masksT[((size_t)(b*64 + tj))*RST + i] = word;
}

// ---------------- kernel 6: greedy scan (UNCHANGED control) ----------------
#define NMS_PLOAD(cc) { \
    int cm = ((cc) > 62) ? 62 : (cc); \
    const u64* colp = mb + (size_t)cm*RST; \
    _Pragma("unroll") \
    for (int k = 0; k < NBLK; ++k) \
        if (k <= cm) pf[k] = colp[(size_t)k*64 + lane]; \
}

#define NMS_PSTORE(cc) { \
    int cm = ((cc) > 62) ? 62 : (cc); \
    int wmax = (cm < NBLK-1) ? cm+1 : NBLK; \
    _Pragma("unroll") \
    for (int k = 0; k < NBLK; ++k) \
        if (k < wmax) colbuf[k*64 + lane] = pf[k]; \
}

__global__ __launch_bounds__(64, 1) void k_nms(const u64* __restrict__ masksT,
                      const float4* __restrict__ topk,
                      float* __restrict__ out)
{
    int b = blockIdx.x;
    int lane = threadIdx.x;        // 0..63

    __shared__ u64 colbuf[NBLK*64];   // current column's history blocks
    __shared__ u32 kmexp[64][64];     // per-(chunk,row) keep select mask
    __shared__ u64 kmw[64];           // per-chunk keep bitmask (valid-masked)

    kmw[lane] = 0ull;
#pragma unroll
    for (int k = 0; k < 64; ++k) kmexp[k][lane] = 0u;

    {
        float* ob = out + (size_t)b*POSTN*5;
        for (int e = lane; e < POSTN*5; e += 64)
            ob[e] = ((e % 5) == 0) ? (float)b : 0.0f;
    }

    const u64* mb = masksT + (size_t)b*64*RST;

    u64 pf[NBLK];
    NMS_PLOAD(0)
    NMS_PSTORE(0)
    NMS_PLOAD(1)

    int kcnt = 0;
    for (int c = 0; c < 63; ++c) {
        u64 acc = 0;
        int kmax = (c < NBLK) ? c : NBLK;
#pragma unroll 8
        for (int k = 0; k < kmax; ++k) {
            u32 mk = kmexp[k][lane];
            u64 v = colbuf[k*64 + lane];
            acc |= v & (((u64)mk << 32) | mk);
        }
        for (int k = NBLK; k < c; ++k) {
            u32 mk = kmexp[k][lane];
            u64 v = mb[(size_t)c*RST + (size_t)k*64 + lane];
            acc |= v & (((u64)mk << 32) | mk);
        }
        u64 w = wave_or64_dpp(acc);
        u64 D = (c < NBLK) ? colbuf[c*64 + lane]
                           : mb[(size_t)c*RST + (size_t)c*64 + lane];
#pragma unroll
        for (int r = 0; r < 64; ++r) {
            u64 dr = readlane64(D, r);
            u64 t;
            asm("s_lshr_b64 %[t], %[w], %[rr]\n\t"
                "s_and_b64 %[t], %[t], 1\n\t"
                "s_cselect_b64 %[t], 0, %[d]\n\t"
                "s_or_b64 %[w], %[w], %[t]"
                : [w]"+s"(w), [t]"=&s"(t)
                : [d]"s"(dr), [rr]"i"(r)
                : "scc");
        }
        u64 kmask = ~w & ((c < 62) ? ~0ull : 0xFFFFFFFFull);
        kcnt += __popcll(kmask);
        if (lane == 0) kmw[c] = kmask;
        kmexp[c][lane] = ((u32)((kmask >> lane) & 1ull)) ? ~0u : 0u;

        if (kcnt >= POSTN || c == 62) break;
        NMS_PSTORE(c+1)
        NMS_PLOAD(c+2)
    }

    u64 keepw = kmw[lane];
    int cnt = __popcll(keepw);
    int pre = cnt;
    for (int d = 1; d < 64; d <<= 1) {
        int t = __shfl_up(pre, d);
        if (lane >= d) pre += t;
    }
    int excl = pre - cnt;
    asm volatile("s_waitcnt vmcnt(0)" ::: "memory");
    u64 wv = keepw; int rk = excl;
    while (wv) {
        int bpos = __ffsll((unsigned long long)wv) - 1;
        wv &= wv - 1;
        if (rk < POSTN) {
            int i = lane*64 + bpos;
            float4 bx = topk[(size_t)b*MROWS + i];
            float* o = out + ((size_t)b*POSTN + rk)*5;
            o[1] = bx.x; o[2] = bx.y; o[3] = bx.z; o[4] = bx.w;
        }
        ++rk;
    }
}

// ---------------- launch ----------------
extern "C" void kernel_launch(void* const* d_in, const int* in_sizes, int n_in,
                              void* d_out, int out_size, void* d_ws, size_t ws_size,
                              hipStream_t stream)
{
    const float* scores  = (const float*)d_in[0];
    const float* deltas  = (const float*)d_in[1];
    const float* im_info = (const float*)d_in[2];
    const float* vrange  = (const float*)d_in[3];
    float* out = (float*)d_out;

    char* ws = (char*)d_ws;
    size_t off = 0;
    auto alloc = [&](size_t bytes) -> void* {
        void* ptr = ws + off;
        off += (bytes + 255) & ~(size_t)255;
        return ptr;
    };
    u32*   fkeys   = (u32*)   alloc((size_t)NB*NPB*sizeof(u32));           // 2.36 MB
    u64*   cand    = (u64*)   alloc((size_t)NB*NREPL*REPCAP*sizeof(u64));  // 1 MB
    float4* topk   = (float4*)alloc((size_t)NB*MROWS*sizeof(float4));      // 256 KB
    u64*   masksT  = (u64*)   alloc((size_t)NB*64*RST*sizeof(u64));        // 8.52 MB
    // zeroed region (single memset): hist12 | ccntRep
    u32*   hist12  = (u32*)   alloc((size_t)NREP*NB*NBINS*sizeof(u32));    // 256 KB
    u32*   ccntRep = (u32*)   alloc((size_t)NB*NREPL*16*sizeof(u32));      // 8 KB
    // outputs written every run (no init needed)
    u32*   thresh12= (u32*)   alloc(256);

    Anchors A;
    gen_anchors(A.v);

    size_t zbytes = (char*)ccntRep + (size_t)NB*NREPL*16*sizeof(u32) - (char*)hist12;
    hipMemsetAsync(hist12, 0, zbytes, stream);

    int total = NB*NPB;
    int blocks = (total + 255)/256;    // 2304, exact (NPB % 256 == 0)
    k_props<<<blocks, 256, 0, stream>>>(scores, deltas, im_info, vrange, A, fkeys, hist12);
    k_findT<<<NB, 1024, 0, stream>>>(hist12, thresh12);
    k_emit<<<blocks, 256, 0, stream>>>(fkeys, thresh12, ccntRep, cand);
    dim3 rgrid(CANDCAP/64, NB);
    k_rank2<<<rgrid, 256, 0, stream>>>(cand, ccntRep, deltas, im_info, A, topk);
    dim3 mgrid(TRI, NB);
    k_mask<<<mgrid, 64, 0, stream>>>(topk, masksT);
    k_nms<<<NB, 64, 0, stream>>>(masksT, topk, out);
}

// Round 17
// 124.284 us; speedup vs baseline: 4.4063x; 1.0804x over previous
//
#include <hip/hip_runtime.h>
#include <cmath>

// ---- problem constants ----
#define WD 128
#define HT 128
#define HW 16384            // H*W
#define NB 4
#define NA 9
#define NPB (NA*HW)         // anchors per batch = 147456
#define TOPN 4000
#define POSTN 1000
#define CANDCAP 8192        // max candidates staged in rank2 LDS
#define REPCAP 1024         // per-replica candidate region
#define NREPL 32            // emit counter replicas per batch
#define MROWS 4096          // padded rows for topk buffer
#define RST 4160            // row stride (u64s) per (b,word) mask stream
#define NTILE 63            // ceil(4000/64)
#define TRI (NTILE*(NTILE+1)/2)   // 2016 upper-triangle tiles
#define NREP 4              // histogram replicas (contention divider)
#define NBINS 4096          // 12-bit histogram
#define NBLK 42             // LDS-staged column blocks (covers exit <= chunk 42)

typedef unsigned long long u64;
typedef unsigned int u32;

struct Anchors { float v[36]; };

// ---------------- host: replicate numpy _generate_anchors exactly ----------------
static void gen_anchors(float* out) {
    double base[4] = {0.0, 0.0, 15.0, 15.0};
    const double ratios[3] = {0.5, 1.0, 2.0};
    const double scales[3] = {8.0, 16.0, 32.0};
    double w = base[2] - base[0] + 1.0;
    double h = base[3] - base[1] + 1.0;
    double xc = base[0] + 0.5 * (w - 1.0);
    double yc = base[1] + 0.5 * (h - 1.0);
    double size = w * h;
    double ra[3][4];
    for (int r = 0; r < 3; ++r) {
        double ws = nearbyint(sqrt(size / ratios[r]));   // np.round = half-even
        double hs = nearbyint(ws * ratios[r]);
        ra[r][0] = xc - 0.5 * (ws - 1.0);
        ra[r][1] = yc - 0.5 * (hs - 1.0);
        ra[r][2] = xc + 0.5 * (ws - 1.0);
        ra[r][3] = yc + 0.5 * (hs - 1.0);
    }
    int k = 0;
    for (int r = 0; r < 3; ++r) {
        double w2 = ra[r][2] - ra[r][0] + 1.0;
        double h2 = ra[r][3] - ra[r][1] + 1.0;
        double x2c = ra[r][0] + 0.5 * (w2 - 1.0);
        double y2c = ra[r][1] + 0.5 * (h2 - 1.0);
        for (int s = 0; s < 3; ++s) {
            double ws = w2 * scales[s], hs = h2 * scales[s];
            out[k*4+0] = (float)(x2c - 0.5 * (ws - 1.0));
            out[k*4+1] = (float)(y2c - 0.5 * (hs - 1.0));
            out[k*4+2] = (float)(x2c + 0.5 * (ws - 1.0));
            out[k*4+3] = (float)(y2c + 0.5 * (hs - 1.0));
            ++k;
        }
    }
}

__device__ __forceinline__ u32 sortable_key(float sc) {
    u32 sb = __float_as_uint(sc);
    return sb ^ ((sb & 0x80000000u) ? 0xFFFFFFFFu : 0x80000000u);
}

__device__ __forceinline__ u64 readlane64(u64 v, int l) {
    u32 lo = (u32)__builtin_amdgcn_readlane((int)(u32)v, l);
    u32 hi = (u32)__builtin_amdgcn_readlane((int)(u32)(v >> 32), l);
    return ((u64)hi << 32) | lo;
}

// 64-lane OR-reduce on the VALU pipe via DPP (rocPRIM pattern).
__device__ __forceinline__ u64 wave_or64_dpp(u64 v) {
    u32 lo = (u32)v, hi = (u32)(v >> 32);
#define DPPOR(x, ctrl) x |= (u32)__builtin_amdgcn_update_dpp(0, (int)(x), ctrl, 0xf, 0xf, false)
    DPPOR(lo, 0x111); DPPOR(lo, 0x112); DPPOR(lo, 0x114); DPPOR(lo, 0x118);
    DPPOR(lo, 0x142); DPPOR(lo, 0x143);
    DPPOR(hi, 0x111); DPPOR(hi, 0x112); DPPOR(hi, 0x114); DPPOR(hi, 0x118);
    DPPOR(hi, 0x142); DPPOR(hi, 0x143);
#undef DPPOR
    u32 rlo = (u32)__builtin_amdgcn_readlane((int)lo, 63);
    u32 rhi = (u32)__builtin_amdgcn_readlane((int)hi, 63);
    return ((u64)rhi << 32) | rlo;
}

// Shared decode: used by k_props (filter) and k_rank2 (winner gather).
// Same source + contract(off) in both -> bit-identical boxes.
__device__ __forceinline__ float4 decode_box(const float* __restrict__ deltas,
                                             const float* __restrict__ im_info,
                                             const Anchors& A, int b, int a, int p)
{
#pragma clang fp contract(off)
    int hh = p >> 7;        // / W
    int ww = p & 127;       // % W
    float sx = (float)(ww * 16);
    float sy = (float)(hh * 16);
    float ax1 = A.v[a*4+0] + sx;
    float ay1 = A.v[a*4+1] + sy;
    float ax2 = A.v[a*4+2] + sx;
    float ay2 = A.v[a*4+3] + sy;
    const float* dbase = deltas + ((size_t)(b*36 + a*4))*HW + p;
    float dx = dbase[0];
    float dy = dbase[HW];
    float dw = dbase[2*HW];
    float dh = dbase[3*HW];
    float aw = ax2 - ax1 + 1.0f;
    float ah = ay2 - ay1 + 1.0f;
    float cx = ax1 + 0.5f*aw;
    float cy = ay1 + 0.5f*ah;
    float pcx = dx*aw + cx;
    float pcy = dy*ah + cy;
    float ew = (float)exp((double)dw);   // correctly-rounded f32 exp
    float eh = (float)exp((double)dh);
    float pw = ew * aw;
    float ph = eh * ah;
    float x1 = pcx - 0.5f*pw;
    float y1 = pcy - 0.5f*ph;
    float x2 = pcx + 0.5f*pw;
    float y2 = pcy + 0.5f*ph;
    float hmax = im_info[b*3+0] - 1.0f;
    float wmax = im_info[b*3+1] - 1.0f;
    x1 = fmaxf(x1, 0.0f); y1 = fmaxf(y1, 0.0f);
    x2 = fmaxf(x2, 0.0f); y2 = fmaxf(y2, 0.0f);
    x1 = fminf(x1, wmax); y1 = fminf(y1, hmax);
    x2 = fminf(x2, wmax); y2 = fminf(y2, hmax);
    return make_float4(x1, y1, x2, y2);
}

// ---------------- kernel 1: decode + filter + key store + 12-bit LDS histogram ----------------
__global__ void k_props(const float* __restrict__ scores,
                        const float* __restrict__ deltas,
                        const float* __restrict__ im_info,
                        const float* __restrict__ valid_range,
                        Anchors A,
                        u32* __restrict__ fkeys,
                        u32* __restrict__ hist12)    // [NREP][NB][NBINS]
{
#pragma clang fp contract(off)
    __shared__ u32 lh[NBINS];   // 16 KB
    int tid = threadIdx.x;
#pragma unroll
    for (int i = 0; i < NBINS/256; ++i) lh[tid + i*256] = 0;
    __syncthreads();

    int n = blockIdx.x * 256 + tid;
    int b = n / NPB;
    int r = n - b*NPB;
    int a = r / HW;
    int p = r - a*HW;

    float4 bx = decode_box(deltas, im_info, A, b, a, p);
    float sc = scores[((size_t)(b*18 + 9 + a))*HW + p];
    float area = (bx.z - bx.x) * (bx.w - bx.y);
    float v0 = valid_range[b*2+0], v1 = valid_range[b*2+1];
    if (area < v0*v0 || area > v1*v1) sc = -1.0f;

    u32 key = sortable_key(sc);
    fkeys[n] = key;
    atomicAdd(&lh[key >> 20], 1u);
    __syncthreads();

    int rep = blockIdx.x & (NREP-1);
    u32* gh = hist12 + ((size_t)rep*NB + b)*NBINS;
#pragma unroll
    for (int i = 0; i < NBINS/256; ++i) {
        u32 v = lh[tid + i*256];
        if (v) atomicAdd(&gh[tid + i*256], v);
    }
}

// ---------------- kernel 2: 12-bit threshold via suffix-scan (1024 threads/batch) ----------------
__global__ void k_findT(const u32* __restrict__ hist12, u32* __restrict__ thresh12)
{
    __shared__ u32 sfx[1024];
    int b = blockIdx.x, t = threadIdx.x;    // 1024 threads; thread owns bins 4t..4t+3
    u32 bin0 = 0, bin1 = 0, bin2 = 0, bin3 = 0;
    for (int rr = 0; rr < NREP; ++rr) {
        const u32* h = hist12 + ((size_t)rr*NB + b)*NBINS + t*4;
        bin0 += h[0]; bin1 += h[1]; bin2 += h[2]; bin3 += h[3];
    }
    u32 s4 = bin0 + bin1 + bin2 + bin3;
    sfx[t] = s4;
    __syncthreads();
    for (int d = 1; d < 1024; d <<= 1) {
        u32 add = (t + d < 1024) ? sfx[t + d] : 0u;
        __syncthreads();
        sfx[t] += add;
        __syncthreads();
    }
    u32 above = (t < 1023) ? sfx[t+1] : 0u;     // sum of bins >= 4(t+1)
    u32 c3 = bin3 + above;
    u32 c2 = bin2 + c3;
    u32 c1 = bin1 + c2;
    u32 c0 = bin0 + c1;
    if (c3 >= TOPN && above < TOPN) thresh12[b] = (u32)(t*4 + 3);
    if (c2 >= TOPN && c3    < TOPN) thresh12[b] = (u32)(t*4 + 2);
    if (c1 >= TOPN && c2    < TOPN) thresh12[b] = (u32)(t*4 + 1);
    if (c0 >= TOPN && c1    < TOPN) thresh12[b] = (u32)(t*4 + 0);
}

// ---------------- kernel 3: emit candidates (replicated wave-aggregated counters) ----------------
// Order within cand is nondeterministic; k_rank2's rank-sort canonicalizes.
__global__ void k_emit(const u32* __restrict__ fkeys,
                       const u32* __restrict__ thresh12,
                       u32* __restrict__ ccntRep,     // [NB*NREPL] stride-16 u32 (64B lines)
                       u64* __restrict__ cand)        // [NB][NREPL][REPCAP]
{
    int tid = threadIdx.x;
    int n = blockIdx.x * 256 + tid;
    int b = n / NPB;
    int r = n - b*NPB;
    int a = r / HW;
    int p = r - a*HW;
    u32 key = fkeys[n];
    bool cond = (key >> 20) >= thresh12[b];
    u64 m = __ballot(cond);
    int lane = tid & 63;
    int rep = blockIdx.x & (NREPL-1);
    if (cond) {
        int leader = __ffsll((unsigned long long)m) - 1;
        u32 base = 0;
        if (lane == leader)
            base = atomicAdd(&ccntRep[(b*NREPL + rep)*16], (u32)__popcll(m));
        base = (u32)__shfl((int)base, leader);
        u32 pos = base + (u32)__popcll(m & ((1ull << lane) - 1ull));
        if (pos < REPCAP) {
            u32 t = (u32)(p*NA + a);               // reference flat index
            cand[((size_t)b*NREPL + rep)*REPCAP + pos] = ((u64)key << 32) | (u32)(~t);
        }
    }
}

// ---------------- kernel 4: region-compact + global rank-sort in LDS + winner re-decode ----------------
__global__ void k_rank2(const u64* __restrict__ cand, const u32* __restrict__ ccntRep,
                        const float* __restrict__ deltas,
                        const float* __restrict__ im_info,
                        Anchors A,
                        float4* __restrict__ topk)
{
    __shared__ u64 kk[CANDCAP];   // 64 KB
    __shared__ u32 ps[256];
    __shared__ u32 rcnt[32];
    __shared__ u32 roff[33];
    int b = blockIdx.y;
    int tid = threadIdx.x;
    if (tid < 32) {
        u32 c = ccntRep[(b*NREPL + tid)*16];
        rcnt[tid] = (c > REPCAP) ? REPCAP : c;
    }
    __syncthreads();
    if (tid == 0) {
        u32 acc = 0;
        for (int i = 0; i < 32; ++i) { roff[i] = acc; acc += rcnt[i]; }
        roff[32] = (acc > CANDCAP) ? CANDCAP : acc;
    }
    __syncthreads();
    u32 N = roff[32];
    if ((u32)(blockIdx.x * 64) >= N) return;    // whole block idle
    for (int rr = 0; rr < 32; ++rr) {
        u32 len = rcnt[rr], base = roff[rr];
        const u64* src = cand + ((size_t)b*NREPL + rr)*REPCAP;
        for (u32 i = tid; i < len; i += 256) {
            u32 g = base + i;
            if (g < CANDCAP) kk[g] = src[i];
        }
    }
    __syncthreads();
    int kl = tid & 63, seg = tid >> 6;
    u32 ki = (u32)(blockIdx.x * 64 + kl);
    u64 mykey = (ki < N) ? kk[ki] : ~0ull;
    u32 segN = (N + 3) >> 2;
    u32 s0 = seg * segN;
    u32 s1 = s0 + segN; if (s1 > N) s1 = N;
    u32 pr = 0;
    u32 i = s0;
    for (; i + 16 <= s1; i += 16) {
        u64 v0 = kk[i+0],  v1 = kk[i+1],  v2 = kk[i+2],  v3 = kk[i+3];
        u64 v4 = kk[i+4],  v5 = kk[i+5],  v6 = kk[i+6],  v7 = kk[i+7];
        u64 v8 = kk[i+8],  v9 = kk[i+9],  va = kk[i+10], vb = kk[i+11];
        u64 vc = kk[i+12], vd = kk[i+13], ve = kk[i+14], vf = kk[i+15];
        pr += (v0 > mykey) + (v1 > mykey) + (v2 > mykey) + (v3 > mykey);
        pr += (v4 > mykey) + (v5 > mykey) + (v6 > mykey) + (v7 > mykey);
        pr += (v8 > mykey) + (v9 > mykey) + (va > mykey) + (vb > mykey);
        pr += (vc > mykey) + (vd > mykey) + (ve > mykey) + (vf > mykey);
    }
    for (; i < s1; ++i) pr += (kk[i] > mykey) ? 1u : 0u;
    ps[tid] = pr;
    __syncthreads();
    if (seg == 0 && ki < N) {
        u32 rank = ps[kl] + ps[kl+64] + ps[kl+128] + ps[kl+192];
        if (rank < TOPN) {
            u32 t = ~((u32)mykey);
            int a = (int)(t % 9u);
            int p = (int)(t / 9u);
            topk[(size_t)b*MROWS + rank] = decode_box(deltas, im_info, A, b, a, p);
        }
    }
}

// ---------------- kernel 5: suppression-mask tiles — UPPER TRIANGLE ONLY ----------------
__global__ void k_mask(const float4* __restrict__ topk, u64* __restrict__ masksT)
{
#pragma clang fp contract(off)
    int L = blockIdx.x;            // 0..TRI-1
    int b = blockIdx.y;
    int ti = (int)((2.0*NTILE + 1.0 -
                    sqrt((2.0*NTILE + 1.0)*(2.0*NTILE + 1.0) - 8.0*(double)L)) * 0.5);
    while ((ti+1)*NTILE - ((ti+1)*ti)/2 <= L) ++ti;          // fixup sqrt rounding
    while (ti*NTILE - (ti*(ti-1))/2 > L) --ti;
    int tj = ti + (L - (ti*NTILE - (ti*(ti-1))/2));

    int r = threadIdx.x;           // 0..63
    int i = ti*64 + r;
    __shared__ float4 cb[64];
    __shared__ float  ca[64];
    u64 word = 0;
    {
        int jj = tj*64 + r;
        float4 cbox = (jj < TOPN) ? topk[(size_t)b*MROWS + jj] : make_float4(0,0,0,0);
        cb[r] = cbox;
        ca[r] = (cbox.z - cbox.x + 1.0f) * (cbox.w - cbox.y + 1.0f);
        __syncthreads();
        if (i < TOPN) {
            float4 rb = topk[(size_t)b*MROWS + i];
            float rarea = (rb.z - rb.x + 1.0f) * (rb.w - rb.y + 1.0f);
            for (int q = 0; q < 64; ++q) {
                float4 cc = cb[q];
                float iw = fminf(rb.z, cc.z) - fmaxf(rb.x, cc.x) + 1.0f;
                float ih = fminf(rb.w, cc.w) - fmaxf(rb.y, cc.y) + 1.0f;
                iw = fmaxf(iw, 0.0f); ih = fmaxf(ih, 0.0f);
                float inter = iw * ih;
                float uni = (rarea + ca[q]) - inter;
                float iou = inter / uni;       // IEEE fp32 division, like numpy
                if (iou > 0.7f) word |= (1ULL << q);
            }
            int nvalid = TOPN - tj*64;
            if (nvalid < 64) word &= ((1ULL << nvalid) - 1ULL);
            if (ti == tj) {
                u64 cm = (r == 63) ? ~0ULL : ((1ULL << (r + 1)) - 1ULL);
                word &= ~cm;                   // enforce j > i
            }
        }
    }
    masksT[((size_t)(b*64 + tj))*RST + i] = word;
}

// ---------------- kernel 6: greedy scan — TWO-WAVE producer/consumer ----------------
// wave0 = serial closure only (single-wave issue rate ~6cy/instr is the floor,
// so instruction count on this wave IS the runtime). wave1 = staging (double-
// buffered colbuf), partial suppression-accumulate from pf registers, and the
// per-chunk finish+DPP-reduce feeding wave0 via LDS. Intra-block barriers only.
#define NMS_PLOAD(cc) { \
    int cm = ((cc) > 62) ? 62 : (cc); \
    const u64* colp = mb + (size_t)cm*RST; \
    _Pragma("unroll") \
    for (int k = 0; k < NBLK; ++k) \
        if (k <= cm) pf[k] = colp[(size_t)k*64 + lane]; \
}

#define NMS_PSTORE(cc, BUF) { \
    int cm = ((cc) > 62) ? 62 : (cc); \
    int wmax = (cm < NBLK-1) ? cm+1 : NBLK; \
    _Pragma("unroll") \
    for (int k = 0; k < NBLK; ++k) \
        if (k < wmax) (BUF)[k*64 + lane] = pf[k]; \
}

__global__ __launch_bounds__(128, 1) void k_nms(const u64* __restrict__ masksT,
                      const float4* __restrict__ topk,
                      float* __restrict__ out)
{
    int b = blockIdx.x;
    int tid = threadIdx.x;
    int lane = tid & 63;
    int wid = tid >> 6;            // 0 = closure wave, 1 = staging wave

    __shared__ u64 colbuf[2][NBLK*64];   // 43 KB double-buffered column history
    __shared__ u32 kmexp[64][64];        // per-(chunk,row) keep select mask
    __shared__ u64 kmw[64];              // per-chunk keep bitmask (valid-masked)
    __shared__ u64 wcomm[1];
    __shared__ int exitf;

    if (wid == 0) {
        kmw[lane] = 0ull;
#pragma unroll
        for (int k = 0; k < 32; ++k) kmexp[k][lane] = 0u;
    } else {
#pragma unroll
        for (int k = 32; k < 64; ++k) kmexp[k][lane] = 0u;
    }
    if (tid == 0) { wcomm[0] = 0ull; exitf = 0; }

    const u64* mb = masksT + (size_t)b*64*RST;

    u64 pf[NBLK];
    u64 accp = 0;

    if (wid == 0) {
        // fill this batch's output with [b,0,0,0,0] while wave1 stages
        float* ob = out + (size_t)b*POSTN*5;
        for (int e = lane; e < POSTN*5; e += 64)
            ob[e] = ((e % 5) == 0) ? (float)b : 0.0f;
    } else {
        NMS_PLOAD(0)
        NMS_PSTORE(0, colbuf[0])
        NMS_PLOAD(1)
    }

    int kcnt = 0;
    for (int c = 0; c < 63; ++c) {
        int cur = c & 1;
        __syncthreads();                           // B1: kmexp[c-1], colbuf[cur] ready
        if (exitf) break;
        if (wid == 1) {
            u64 acc = accp;
            if (c > 0) {
                u32 mk = kmexp[c-1][lane];
                u64 v = (c-1 < NBLK) ? colbuf[cur][(c-1)*64 + lane]
                                     : mb[(size_t)c*RST + (size_t)(c-1)*64 + lane];
                acc |= v & (((u64)mk << 32) | mk);
                for (int k = NBLK; k < c-1; ++k) { // fallback (exit<=42 => never)
                    u32 m2 = kmexp[k][lane];
                    u64 v2 = mb[(size_t)c*RST + (size_t)k*64 + lane];
                    acc |= v2 & (((u64)m2 << 32) | m2);
                }
            }
            u64 wv = wave_or64_dpp(acc);
            if (lane == 0) wcomm[0] = wv;
        }
        __syncthreads();                           // B2: wcomm ready
        if (wid == 0) {
            u64 wl = wcomm[0];
            u32 wlo = (u32)__builtin_amdgcn_readfirstlane((int)(u32)wl);
            u32 whi = (u32)__builtin_amdgcn_readfirstlane((int)(u32)(wl >> 32));
            u64 w = ((u64)whi << 32) | wlo;
            u64 D = (c < NBLK) ? colbuf[cur][c*64 + lane]
                               : mb[(size_t)c*RST + (size_t)c*64 + lane];
#pragma unroll
            for (int r = 0; r < 64; ++r) {
                u64 dr = readlane64(D, r);
                u64 t;
                asm("s_lshr_b64 %[t], %[w], %[rr]\n\t"
                    "s_and_b64 %[t], %[t], 1\n\t"
                    "s_cselect_b64 %[t], 0, %[d]\n\t"
                    "s_or_b64 %[w], %[w], %[t]"
                    : [w]"+s"(w), [t]"=&s"(t)
                    : [d]"s"(dr), [rr]"i"(r)
                    : "scc");
            }
            u64 kmask = ~w & ((c < 62) ? ~0ull : 0xFFFFFFFFull);
            kcnt += __popcll(kmask);
            if (lane == 0) {
                kmw[c] = kmask;
                if (kcnt >= POSTN || c == 62) exitf = 1;
            }
            kmexp[c][lane] = ((u32)((kmask >> lane) & 1ull)) ? ~0u : 0u;
        } else {
            // stage column c+1 into the other buffer; partial-acc from pf; load c+2
            NMS_PSTORE(c+1, colbuf[cur^1])
            u64 ap = 0;
            int km = (c < NBLK) ? c : NBLK;        // acc_part(c+1) covers k < c
#pragma unroll
            for (int k = 0; k < NBLK; ++k) {
                if (k < km) {
                    u32 mk = kmexp[k][lane];
                    ap |= pf[k] & (((u64)mk << 32) | mk);
                }
            }
            accp = ap;
            NMS_PLOAD(c+2)
        }
    }

    // output enumeration by wave0 only (kmw[c]=0 for unprocessed chunks)
    if (wid == 0) {
        u64 keepw = kmw[lane];
        int cnt = __popcll(keepw);
        int pre = cnt;
        for (int d = 1; d < 64; d <<= 1) {
            int t = __shfl_up(pre, d);
            if (lane >= d) pre += t;
        }
        int excl = pre - cnt;
        asm volatile("s_waitcnt vmcnt(0)" ::: "memory");  // fill stores drained
        u64 wv = keepw; int rk = excl;
        while (wv) {
            int bpos = __ffsll((unsigned long long)wv) - 1;
            wv &= wv - 1;
            if (rk < POSTN) {
                int i = lane*64 + bpos;
                float4 bx = topk[(size_t)b*MROWS + i];
                float* o = out + ((size_t)b*POSTN + rk)*5;
                o[1] = bx.x; o[2] = bx.y; o[3] = bx.z; o[4] = bx.w;
            }
            ++rk;
        }
    }
}

// ---------------- launch ----------------
extern "C" void kernel_launch(void* const* d_in, const int* in_sizes, int n_in,
                              void* d_out, int out_size, void* d_ws, size_t ws_size,
                              hipStream_t stream)
{
    const float* scores  = (const float*)d_in[0];
    const float* deltas  = (const float*)d_in[1];
    const float* im_info = (const float*)d_in[2];
    const float* vrange  = (const float*)d_in[3];
    float* out = (float*)d_out;

    char* ws = (char*)d_ws;
    size_t off = 0;
    auto alloc = [&](size_t bytes) -> void* {
        void* ptr = ws + off;
        off += (bytes + 255) & ~(size_t)255;
        return ptr;
    };
    u32*   fkeys   = (u32*)   alloc((size_t)NB*NPB*sizeof(u32));           // 2.36 MB
    u64*   cand    = (u64*)   alloc((size_t)NB*NREPL*REPCAP*sizeof(u64));  // 1 MB
    float4* topk   = (float4*)alloc((size_t)NB*MROWS*sizeof(float4));      // 256 KB
    u64*   masksT  = (u64*)   alloc((size_t)NB*64*RST*sizeof(u64));        // 8.52 MB
    // zeroed region (single memset): hist12 | ccntRep
    u32*   hist12  = (u32*)   alloc((size_t)NREP*NB*NBINS*sizeof(u32));    // 256 KB
    u32*   ccntRep = (u32*)   alloc((size_t)NB*NREPL*16*sizeof(u32));      // 8 KB
    // outputs written every run (no init needed)
    u32*   thresh12= (u32*)   alloc(256);

    Anchors A;
    gen_anchors(A.v);

    size_t zbytes = (char*)ccntRep + (size_t)NB*NREPL*16*sizeof(u32) - (char*)hist12;
    hipMemsetAsync(hist12, 0, zbytes, stream);

    int total = NB*NPB;
    int blocks = (total + 255)/256;    // 2304, exact (NPB % 256 == 0)
    k_props<<<blocks, 256, 0, stream>>>(scores, deltas, im_info, vrange, A, fkeys, hist12);
    k_findT<<<NB, 1024, 0, stream>>>(hist12, thresh12);
    k_emit<<<blocks, 256, 0, stream>>>(fkeys, thresh12, ccntRep, cand);
    dim3 rgrid(CANDCAP/64, NB);
    k_rank2<<<rgrid, 256, 0, stream>>>(cand, ccntRep, deltas, im_info, A, topk);
    dim3 mgrid(TRI, NB);
    k_mask<<<mgrid, 64, 0, stream>>>(topk, masksT);
    k_nms<<<NB, 128, 0, stream>>>(masksT, topk, out);
}

// Round 18
// 124.006 us; speedup vs baseline: 4.4162x; 1.0022x over previous
//
#include <hip/hip_runtime.h>
#include <cmath>

// ---- problem constants ----
#define WD 128
#define HT 128
#define HW 16384            // H*W
#define NB 4
#define NA 9
#define NPB (NA*HW)         // anchors per batch = 147456
#define TOPN 4000
#define POSTN 1000
#define CANDCAP 8192        // max candidates staged in rank2 LDS
#define REPCAP 1024         // per-replica candidate region
#define NREPL 32            // emit counter replicas per batch
#define MROWS 4096          // padded rows for topk buffer
#define RST 4160            // row stride (u64s) per (b,word) mask stream
#define NTILE 63            // ceil(4000/64)
#define TRI (NTILE*(NTILE+1)/2)   // 2016 upper-triangle tiles
#define NREP 4              // histogram replicas (contention divider)
#define NBINS 4096          // 12-bit histogram
#define NBLK 42             // LDS-staged column blocks (covers exit <= chunk 42)

typedef unsigned long long u64;
typedef unsigned int u32;

struct Anchors { float v[36]; };

// ---------------- host: replicate numpy _generate_anchors exactly ----------------
static void gen_anchors(float* out) {
    double base[4] = {0.0, 0.0, 15.0, 15.0};
    const double ratios[3] = {0.5, 1.0, 2.0};
    const double scales[3] = {8.0, 16.0, 32.0};
    double w = base[2] - base[0] + 1.0;
    double h = base[3] - base[1] + 1.0;
    double xc = base[0] + 0.5 * (w - 1.0);
    double yc = base[1] + 0.5 * (h - 1.0);
    double size = w * h;
    double ra[3][4];
    for (int r = 0; r < 3; ++r) {
        double ws = nearbyint(sqrt(size / ratios[r]));   // np.round = half-even
        double hs = nearbyint(ws * ratios[r]);
        ra[r][0] = xc - 0.5 * (ws - 1.0);
        ra[r][1] = yc - 0.5 * (hs - 1.0);
        ra[r][2] = xc + 0.5 * (ws - 1.0);
        ra[r][3] = yc + 0.5 * (hs - 1.0);
    }
    int k = 0;
    for (int r = 0; r < 3; ++r) {
        double w2 = ra[r][2] - ra[r][0] + 1.0;
        double h2 = ra[r][3] - ra[r][1] + 1.0;
        double x2c = ra[r][0] + 0.5 * (w2 - 1.0);
        double y2c = ra[r][1] + 0.5 * (h2 - 1.0);
        for (int s = 0; s < 3; ++s) {
            double ws = w2 * scales[s], hs = h2 * scales[s];
            out[k*4+0] = (float)(x2c - 0.5 * (ws - 1.0));
            out[k*4+1] = (float)(y2c - 0.5 * (hs - 1.0));
            out[k*4+2] = (float)(x2c + 0.5 * (ws - 1.0));
            out[k*4+3] = (float)(y2c + 0.5 * (hs - 1.0));
            ++k;
        }
    }
}

__device__ __forceinline__ u32 sortable_key(float sc) {
    u32 sb = __float_as_uint(sc);
    return sb ^ ((sb & 0x80000000u) ? 0xFFFFFFFFu : 0x80000000u);
}

__device__ __forceinline__ u64 readlane64(u64 v, int l) {
    u32 lo = (u32)__builtin_amdgcn_readlane((int)(u32)v, l);
    u32 hi = (u32)__builtin_amdgcn_readlane((int)(u32)(v >> 32), l);
    return ((u64)hi << 32) | lo;
}

// 64-lane OR-reduce on the VALU pipe via DPP (rocPRIM pattern).
__device__ __forceinline__ u64 wave_or64_dpp(u64 v) {
    u32 lo = (u32)v, hi = (u32)(v >> 32);
#define DPPOR(x, ctrl) x |= (u32)__builtin_amdgcn_update_dpp(0, (int)(x), ctrl, 0xf, 0xf, false)
    DPPOR(lo, 0x111); DPPOR(lo, 0x112); DPPOR(lo, 0x114); DPPOR(lo, 0x118);
    DPPOR(lo, 0x142); DPPOR(lo, 0x143);
    DPPOR(hi, 0x111); DPPOR(hi, 0x112); DPPOR(hi, 0x114); DPPOR(hi, 0x118);
    DPPOR(hi, 0x142); DPPOR(hi, 0x143);
#undef DPPOR
    u32 rlo = (u32)__builtin_amdgcn_readlane((int)lo, 63);
    u32 rhi = (u32)__builtin_amdgcn_readlane((int)hi, 63);
    return ((u64)rhi << 32) | rlo;
}

// Shared decode: used by k_props (filter) and k_rank2 (winner gather).
// Same source + contract(off) in both -> bit-identical boxes.
__device__ __forceinline__ float4 decode_box(const float* __restrict__ deltas,
                                             const float* __restrict__ im_info,
                                             const Anchors& A, int b, int a, int p)
{
#pragma clang fp contract(off)
    int hh = p >> 7;        // / W
    int ww = p & 127;       // % W
    float sx = (float)(ww * 16);
    float sy = (float)(hh * 16);
    float ax1 = A.v[a*4+0] + sx;
    float ay1 = A.v[a*4+1] + sy;
    float ax2 = A.v[a*4+2] + sx;
    float ay2 = A.v[a*4+3] + sy;
    const float* dbase = deltas + ((size_t)(b*36 + a*4))*HW + p;
    float dx = dbase[0];
    float dy = dbase[HW];
    float dw = dbase[2*HW];
    float dh = dbase[3*HW];
    float aw = ax2 - ax1 + 1.0f;
    float ah = ay2 - ay1 + 1.0f;
    float cx = ax1 + 0.5f*aw;
    float cy = ay1 + 0.5f*ah;
    float pcx = dx*aw + cx;
    float pcy = dy*ah + cy;
    float ew = (float)exp((double)dw);   // correctly-rounded f32 exp
    float eh = (float)exp((double)dh);
    float pw = ew * aw;
    float ph = eh * ah;
    float x1 = pcx - 0.5f*pw;
    float y1 = pcy - 0.5f*ph;
    float x2 = pcx + 0.5f*pw;
    float y2 = pcy + 0.5f*ph;
    float hmax = im_info[b*3+0] - 1.0f;
    float wmax = im_info[b*3+1] - 1.0f;
    x1 = fmaxf(x1, 0.0f); y1 = fmaxf(y1, 0.0f);
    x2 = fmaxf(x2, 0.0f); y2 = fmaxf(y2, 0.0f);
    x1 = fminf(x1, wmax); y1 = fminf(y1, hmax);
    x2 = fminf(x2, wmax); y2 = fminf(y2, hmax);
    return make_float4(x1, y1, x2, y2);
}

// ---------------- kernel 1: decode + filter + key store + 12-bit LDS histogram ----------------
__global__ void k_props(const float* __restrict__ scores,
                        const float* __restrict__ deltas,
                        const float* __restrict__ im_info,
                        const float* __restrict__ valid_range,
                        Anchors A,
                        u32* __restrict__ fkeys,
                        u32* __restrict__ hist12)    // [NREP][NB][NBINS]
{
#pragma clang fp contract(off)
    __shared__ u32 lh[NBINS];   // 16 KB
    int tid = threadIdx.x;
#pragma unroll
    for (int i = 0; i < NBINS/256; ++i) lh[tid + i*256] = 0;
    __syncthreads();

    int n = blockIdx.x * 256 + tid;
    int b = n / NPB;
    int r = n - b*NPB;
    int a = r / HW;
    int p = r - a*HW;

    float4 bx = decode_box(deltas, im_info, A, b, a, p);
    float sc = scores[((size_t)(b*18 + 9 + a))*HW + p];
    float area = (bx.z - bx.x) * (bx.w - bx.y);
    float v0 = valid_range[b*2+0], v1 = valid_range[b*2+1];
    if (area < v0*v0 || area > v1*v1) sc = -1.0f;

    u32 key = sortable_key(sc);
    fkeys[n] = key;
    atomicAdd(&lh[key >> 20], 1u);
    __syncthreads();

    int rep = blockIdx.x & (NREP-1);
    u32* gh = hist12 + ((size_t)rep*NB + b)*NBINS;
#pragma unroll
    for (int i = 0; i < NBINS/256; ++i) {
        u32 v = lh[tid + i*256];
        if (v) atomicAdd(&gh[tid + i*256], v);
    }
}

// ---------------- kernel 2: 12-bit threshold via suffix-scan (1024 threads/batch) ----------------
__global__ void k_findT(const u32* __restrict__ hist12, u32* __restrict__ thresh12)
{
    __shared__ u32 sfx[1024];
    int b = blockIdx.x, t = threadIdx.x;    // 1024 threads; thread owns bins 4t..4t+3
    u32 bin0 = 0, bin1 = 0, bin2 = 0, bin3 = 0;
    for (int rr = 0; rr < NREP; ++rr) {
        const u32* h = hist12 + ((size_t)rr*NB + b)*NBINS + t*4;
        bin0 += h[0]; bin1 += h[1]; bin2 += h[2]; bin3 += h[3];
    }
    u32 s4 = bin0 + bin1 + bin2 + bin3;
    sfx[t] = s4;
    __syncthreads();
    for (int d = 1; d < 1024; d <<= 1) {
        u32 add = (t + d < 1024) ? sfx[t + d] : 0u;
        __syncthreads();
        sfx[t] += add;
        __syncthreads();
    }
    u32 above = (t < 1023) ? sfx[t+1] : 0u;     // sum of bins >= 4(t+1)
    u32 c3 = bin3 + above;
    u32 c2 = bin2 + c3;
    u32 c1 = bin1 + c2;
    u32 c0 = bin0 + c1;
    if (c3 >= TOPN && above < TOPN) thresh12[b] = (u32)(t*4 + 3);
    if (c2 >= TOPN && c3    < TOPN) thresh12[b] = (u32)(t*4 + 2);
    if (c1 >= TOPN && c2    < TOPN) thresh12[b] = (u32)(t*4 + 1);
    if (c0 >= TOPN && c1    < TOPN) thresh12[b] = (u32)(t*4 + 0);
}

// ---------------- kernel 3: emit candidates (replicated wave-aggregated counters) ----------------
// Order within cand is nondeterministic; k_rank2's rank-sort canonicalizes.
__global__ void k_emit(const u32* __restrict__ fkeys,
                       const u32* __restrict__ thresh12,
                       u32* __restrict__ ccntRep,     // [NB*NREPL] stride-16 u32 (64B lines)
                       u64* __restrict__ cand)        // [NB][NREPL][REPCAP]
{
    int tid = threadIdx.x;
    int n = blockIdx.x * 256 + tid;
    int b = n / NPB;
    int r = n - b*NPB;
    int a = r / HW;
    int p = r - a*HW;
    u32 key = fkeys[n];
    bool cond = (key >> 20) >= thresh12[b];
    u64 m = __ballot(cond);
    int lane = tid & 63;
    int rep = blockIdx.x & (NREPL-1);
    if (cond) {
        int leader = __ffsll((unsigned long long)m) - 1;
        u32 base = 0;
        if (lane == leader)
            base = atomicAdd(&ccntRep[(b*NREPL + rep)*16], (u32)__popcll(m));
        base = (u32)__shfl((int)base, leader);
        u32 pos = base + (u32)__popcll(m & ((1ull << lane) - 1ull));
        if (pos < REPCAP) {
            u32 t = (u32)(p*NA + a);               // reference flat index
            cand[((size_t)b*NREPL + rep)*REPCAP + pos] = ((u64)key << 32) | (u32)(~t);
        }
    }
}

// ---------------- kernel 4: region-compact + global rank-sort in LDS + winner re-decode ----------------
__global__ void k_rank2(const u64* __restrict__ cand, const u32* __restrict__ ccntRep,
                        const float* __restrict__ deltas,
                        const float* __restrict__ im_info,
                        Anchors A,
                        float4* __restrict__ topk)
{
    __shared__ u64 kk[CANDCAP];   // 64 KB
    __shared__ u32 ps[256];
    __shared__ u32 rcnt[32];
    __shared__ u32 roff[33];
    int b = blockIdx.y;
    int tid = threadIdx.x;
    if (tid < 32) {
        u32 c = ccntRep[(b*NREPL + tid)*16];
        rcnt[tid] = (c > REPCAP) ? REPCAP : c;
    }
    __syncthreads();
    if (tid == 0) {
        u32 acc = 0;
        for (int i = 0; i < 32; ++i) { roff[i] = acc; acc += rcnt[i]; }
        roff[32] = (acc > CANDCAP) ? CANDCAP : acc;
    }
    __syncthreads();
    u32 N = roff[32];
    if ((u32)(blockIdx.x * 64) >= N) return;    // whole block idle
    for (int rr = 0; rr < 32; ++rr) {
        u32 len = rcnt[rr], base = roff[rr];
        const u64* src = cand + ((size_t)b*NREPL + rr)*REPCAP;
        for (u32 i = tid; i < len; i += 256) {
            u32 g = base + i;
            if (g < CANDCAP) kk[g] = src[i];
        }
    }
    __syncthreads();
    int kl = tid & 63, seg = tid >> 6;
    u32 ki = (u32)(blockIdx.x * 64 + kl);
    u64 mykey = (ki < N) ? kk[ki] : ~0ull;
    u32 segN = (N + 3) >> 2;
    u32 s0 = seg * segN;
    u32 s1 = s0 + segN; if (s1 > N) s1 = N;
    u32 pr = 0;
    u32 i = s0;
    for (; i + 16 <= s1; i += 16) {
        u64 v0 = kk[i+0],  v1 = kk[i+1],  v2 = kk[i+2],  v3 = kk[i+3];
        u64 v4 = kk[i+4],  v5 = kk[i+5],  v6 = kk[i+6],  v7 = kk[i+7];
        u64 v8 = kk[i+8],  v9 = kk[i+9],  va = kk[i+10], vb = kk[i+11];
        u64 vc = kk[i+12], vd = kk[i+13], ve = kk[i+14], vf = kk[i+15];
        pr += (v0 > mykey) + (v1 > mykey) + (v2 > mykey) + (v3 > mykey);
        pr += (v4 > mykey) + (v5 > mykey) + (v6 > mykey) + (v7 > mykey);
        pr += (v8 > mykey) + (v9 > mykey) + (va > mykey) + (vb > mykey);
        pr += (vc > mykey) + (vd > mykey) + (ve > mykey) + (vf > mykey);
    }
    for (; i < s1; ++i) pr += (kk[i] > mykey) ? 1u : 0u;
    ps[tid] = pr;
    __syncthreads();
    if (seg == 0 && ki < N) {
        u32 rank = ps[kl] + ps[kl+64] + ps[kl+128] + ps[kl+192];
        if (rank < TOPN) {
            u32 t = ~((u32)mykey);
            int a = (int)(t % 9u);
            int p = (int)(t / 9u);
            topk[(size_t)b*MROWS + rank] = decode_box(deltas, im_info, A, b, a, p);
        }
    }
}

// ---------------- kernel 5: suppression-mask tiles — UPPER TRIANGLE ONLY ----------------
__global__ void k_mask(const float4* __restrict__ topk, u64* __restrict__ masksT)
{
#pragma clang fp contract(off)
    int L = blockIdx.x;            // 0..TRI-1
    int b = blockIdx.y;
    int ti = (int)((2.0*NTILE + 1.0 -
                    sqrt((2.0*NTILE + 1.0)*(2.0*NTILE + 1.0) - 8.0*(double)L)) * 0.5);
    while ((ti+1)*NTILE - ((ti+1)*ti)/2 <= L) ++ti;          // fixup sqrt rounding
    while (ti*NTILE - (ti*(ti-1))/2 > L) --ti;
    int tj = ti + (L - (ti*NTILE - (ti*(ti-1))/2));

    int r = threadIdx.x;           // 0..63
    int i = ti*64 + r;
    __shared__ float4 cb[64];
    __shared__ float  ca[64];
    u64 word = 0;
    {
        int jj = tj*64 + r;
        float4 cbox = (jj < TOPN) ? topk[(size_t)b*MROWS + jj] : make_float4(0,0,0,0);
        cb[r] = cbox;
        ca[r] = (cbox.z - cbox.x + 1.0f) * (cbox.w - cbox.y + 1.0f);
        __syncthreads();
        if (i < TOPN) {
            float4 rb = topk[(size_t)b*MROWS + i];
            float rarea = (rb.z - rb.x + 1.0f) * (rb.w - rb.y + 1.0f);
            for (int q = 0; q < 64; ++q) {
                float4 cc = cb[q];
                float iw = fminf(rb.z, cc.z) - fmaxf(rb.x, cc.x) + 1.0f;
                float ih = fminf(rb.w, cc.w) - fmaxf(rb.y, cc.y) + 1.0f;
                iw = fmaxf(iw, 0.0f); ih = fmaxf(ih, 0.0f);
                float inter = iw * ih;
                float uni = (rarea + ca[q]) - inter;
                float iou = inter / uni;       // IEEE fp32 division, like numpy
                if (iou > 0.7f) word |= (1ULL << q);
            }
            int nvalid = TOPN - tj*64;
            if (nvalid < 64) word &= ((1ULL << nvalid) - 1ULL);
            if (ti == tj) {
                u64 cm = (r == 63) ? ~0ULL : ((1ULL << (r + 1)) - 1ULL);
                word &= ~cm;                   // enforce j > i
            }
        }
    }
    masksT[((size_t)(b*64 + tj))*RST + i] = word;
}

// ---------------- kernel 6: greedy scan — TWO-WAVE producer/consumer ----------------
// wave0 = serial closure only; wave1 = staging + partial acc + finish-reduce.
// Closure runs in 16-row groups: 32 hoisted v_readlane fill drs[] (SGPRs),
// then a pure-SALU 3-op/row chain (s_bitcmp1_b64 / s_cselect / s_or) —
// amortizes the VALU->SALU SGPR hazard that dominated the per-row cost.
#define NMS_PLOAD(cc) { \
    int cm = ((cc) > 62) ? 62 : (cc); \
    const u64* colp = mb + (size_t)cm*RST; \
    _Pragma("unroll") \
    for (int k = 0; k < NBLK; ++k) \
        if (k <= cm) pf[k] = colp[(size_t)k*64 + lane]; \
}

#define NMS_PSTORE(cc, BUF) { \
    int cm = ((cc) > 62) ? 62 : (cc); \
    int wmax = (cm < NBLK-1) ? cm+1 : NBLK; \
    _Pragma("unroll") \
    for (int k = 0; k < NBLK; ++k) \
        if (k < wmax) (BUF)[k*64 + lane] = pf[k]; \
}

__global__ __launch_bounds__(128, 1) void k_nms(const u64* __restrict__ masksT,
                      const float4* __restrict__ topk,
                      float* __restrict__ out)
{
    int b = blockIdx.x;
    int tid = threadIdx.x;
    int lane = tid & 63;
    int wid = tid >> 6;            // 0 = closure wave, 1 = staging wave

    __shared__ u64 colbuf[2][NBLK*64];   // 43 KB double-buffered column history
    __shared__ u32 kmexp[64][64];        // per-(chunk,row) keep select mask
    __shared__ u64 kmw[64];              // per-chunk keep bitmask (valid-masked)
    __shared__ u64 wcomm[1];
    __shared__ int exitf;

    if (wid == 0) {
        kmw[lane] = 0ull;
#pragma unroll
        for (int k = 0; k < 32; ++k) kmexp[k][lane] = 0u;
    } else {
#pragma unroll
        for (int k = 32; k < 64; ++k) kmexp[k][lane] = 0u;
    }
    if (tid == 0) { wcomm[0] = 0ull; exitf = 0; }

    const u64* mb = masksT + (size_t)b*64*RST;

    u64 pf[NBLK];
    u64 accp = 0;

    if (wid == 0) {
        // fill this batch's output with [b,0,0,0,0] while wave1 stages
        float* ob = out + (size_t)b*POSTN*5;
        for (int e = lane; e < POSTN*5; e += 64)
            ob[e] = ((e % 5) == 0) ? (float)b : 0.0f;
    } else {
        NMS_PLOAD(0)
        NMS_PSTORE(0, colbuf[0])
        NMS_PLOAD(1)
    }

    int kcnt = 0;
    for (int c = 0; c < 63; ++c) {
        int cur = c & 1;
        __syncthreads();                           // B1: kmexp[c-1], colbuf[cur] ready
        if (exitf) break;
        if (wid == 1) {
            u64 acc = accp;
            if (c > 0) {
                u32 mk = kmexp[c-1][lane];
                u64 v = (c-1 < NBLK) ? colbuf[cur][(c-1)*64 + lane]
                                     : mb[(size_t)c*RST + (size_t)(c-1)*64 + lane];
                acc |= v & (((u64)mk << 32) | mk);
                for (int k = NBLK; k < c-1; ++k) { // fallback (exit<=42 => never)
                    u32 m2 = kmexp[k][lane];
                    u64 v2 = mb[(size_t)c*RST + (size_t)k*64 + lane];
                    acc |= v2 & (((u64)m2 << 32) | m2);
                }
            }
            u64 wv = wave_or64_dpp(acc);
            if (lane == 0) wcomm[0] = wv;
        }
        __syncthreads();                           // B2: wcomm ready
        if (wid == 0) {
            u64 wl = wcomm[0];
            u32 wlo = (u32)__builtin_amdgcn_readfirstlane((int)(u32)wl);
            u32 whi = (u32)__builtin_amdgcn_readfirstlane((int)(u32)(wl >> 32));
            u64 w = ((u64)whi << 32) | wlo;
            u64 D = (c < NBLK) ? colbuf[cur][c*64 + lane]
                               : mb[(size_t)c*RST + (size_t)c*64 + lane];
#pragma unroll
            for (int g = 0; g < 4; ++g) {
                u64 drs[16];
#pragma unroll
                for (int j = 0; j < 16; ++j) drs[j] = readlane64(D, g*16 + j);
#pragma unroll
                for (int j = 0; j < 16; ++j) {
                    u64 t;
                    asm("s_bitcmp1_b64 %[w], %[rr]\n\t"
                        "s_cselect_b64 %[t], 0, %[d]\n\t"
                        "s_or_b64 %[w], %[w], %[t]"
                        : [w]"+s"(w), [t]"=&s"(t)
                        : [d]"s"(drs[j]), [rr]"i"(g*16 + j)
                        : "scc");
                }
            }
            u64 kmask = ~w & ((c < 62) ? ~0ull : 0xFFFFFFFFull);
            kcnt += __popcll(kmask);
            if (lane == 0) {
                kmw[c] = kmask;
                if (kcnt >= POSTN || c == 62) exitf = 1;
            }
            kmexp[c][lane] = ((u32)((kmask >> lane) & 1ull)) ? ~0u : 0u;
        } else {
            // stage column c+1 into the other buffer; partial-acc from pf; load c+2
            NMS_PSTORE(c+1, colbuf[cur^1])
            u64 ap = 0;
            int km = (c < NBLK) ? c : NBLK;        // acc_part(c+1) covers k < c
#pragma unroll
            for (int k = 0; k < NBLK; ++k) {
                if (k < km) {
                    u32 mk = kmexp[k][lane];
                    ap |= pf[k] & (((u64)mk << 32) | mk);
                }
            }
            accp = ap;
            NMS_PLOAD(c+2)
        }
    }

    // output enumeration by wave0 only (kmw[c]=0 for unprocessed chunks)
    if (wid == 0) {
        u64 keepw = kmw[lane];
        int cnt = __popcll(keepw);
        int pre = cnt;
        for (int d = 1; d < 64; d <<= 1) {
            int t = __shfl_up(pre, d);
            if (lane >= d) pre += t;
        }
        int excl = pre - cnt;
        asm volatile("s_waitcnt vmcnt(0)" ::: "memory");  // fill stores drained
        u64 wv = keepw; int rk = excl;
        while (wv) {
            int bpos = __ffsll((unsigned long long)wv) - 1;
            wv &= wv - 1;
            if (rk < POSTN) {
                int i = lane*64 + bpos;
                float4 bx = topk[(size_t)b*MROWS + i];
                float* o = out + ((size_t)b*POSTN + rk)*5;
                o[1] = bx.x; o[2] = bx.y; o[3] = bx.z; o[4] = bx.w;
            }
            ++rk;
        }
    }
}

// ---------------- launch ----------------
extern "C" void kernel_launch(void* const* d_in, const int* in_sizes, int n_in,
                              void* d_out, int out_size, void* d_ws, size_t ws_size,
                              hipStream_t stream)
{
    const float* scores  = (const float*)d_in[0];
    const float* deltas  = (const float*)d_in[1];
    const float* im_info = (const float*)d_in[2];
    const float* vrange  = (const float*)d_in[3];
    float* out = (float*)d_out;

    char* ws = (char*)d_ws;
    size_t off = 0;
    auto alloc = [&](size_t bytes) -> void* {
        void* ptr = ws + off;
        off += (bytes + 255) & ~(size_t)255;
        return ptr;
    };
    u32*   fkeys   = (u32*)   alloc((size_t)NB*NPB*sizeof(u32));           // 2.36 MB
    u64*   cand    = (u64*)   alloc((size_t)NB*NREPL*REPCAP*sizeof(u64));  // 1 MB
    float4* topk   = (float4*)alloc((size_t)NB*MROWS*sizeof(float4));      // 256 KB
    u64*   masksT  = (u64*)   alloc((size_t)NB*64*RST*sizeof(u64));        // 8.52 MB
    // zeroed region (single memset): hist12 | ccntRep
    u32*   hist12  = (u32*)   alloc((size_t)NREP*NB*NBINS*sizeof(u32));    // 256 KB
    u32*   ccntRep = (u32*)   alloc((size_t)NB*NREPL*16*sizeof(u32));      // 8 KB
    // outputs written every run (no init needed)
    u32*   thresh12= (u32*)   alloc(256);

    Anchors A;
    gen_anchors(A.v);

    size_t zbytes = (char*)ccntRep + (size_t)NB*NREPL*16*sizeof(u32) - (char*)hist12;
    hipMemsetAsync(hist12, 0, zbytes, stream);

    int total = NB*NPB;
    int blocks = (total + 255)/256;    // 2304, exact (NPB % 256 == 0)
    k_props<<<blocks, 256, 0, stream>>>(scores, deltas, im_info, vrange, A, fkeys, hist12);
    k_findT<<<NB, 1024, 0, stream>>>(hist12, thresh12);
    k_emit<<<blocks, 256, 0, stream>>>(fkeys, thresh12, ccntRep, cand);
    dim3 rgrid(CANDCAP/64, NB);
    k_rank2<<<rgrid, 256, 0, stream>>>(cand, ccntRep, deltas, im_info, A, topk);
    dim3 mgrid(TRI, NB);
    k_mask<<<mgrid, 64, 0, stream>>>(topk, masksT);
    k_nms<<<NB, 128, 0, stream>>>(masksT, topk, out);
}

// Round 20
// 121.483 us; speedup vs baseline: 4.5079x; 1.0208x over previous
//
#include <hip/hip_runtime.h>
#include <cmath>

// ---- problem constants ----
#define WD 128
#define HT 128
#define HW 16384            // H*W
#define NB 4
#define NA 9
#define NPB (NA*HW)         // anchors per batch = 147456
#define TOPN 4000
#define POSTN 1000
#define CANDCAP 8192        // max candidates staged in rank2 LDS
#define REPCAP 1024         // per-replica candidate region
#define NREPL 32            // emit counter replicas per batch
#define MROWS 4096          // padded rows for topk buffer
#define RST 4160            // row stride (u64s) per (b,word) mask stream
#define NTILE 63            // ceil(4000/64)
#define TRI (NTILE*(NTILE+1)/2)   // 2016 upper-triangle tiles
#define NREP 4              // histogram replicas (contention divider)
#define NBINS 4096          // 12-bit histogram
#define NBLK 42             // LDS-staged column blocks (covers exit <= chunk 42)
#define HBLK 21             // half of NBLK (per acc wave)

typedef unsigned long long u64;
typedef unsigned int u32;

struct Anchors { float v[36]; };

// ---------------- host: replicate numpy _generate_anchors exactly ----------------
static void gen_anchors(float* out) {
    double base[4] = {0.0, 0.0, 15.0, 15.0};
    const double ratios[3] = {0.5, 1.0, 2.0};
    const double scales[3] = {8.0, 16.0, 32.0};
    double w = base[2] - base[0] + 1.0;
    double h = base[3] - base[1] + 1.0;
    double xc = base[0] + 0.5 * (w - 1.0);
    double yc = base[1] + 0.5 * (h - 1.0);
    double size = w * h;
    double ra[3][4];
    for (int r = 0; r < 3; ++r) {
        double ws = nearbyint(sqrt(size / ratios[r]));   // np.round = half-even
        double hs = nearbyint(ws * ratios[r]);
        ra[r][0] = xc - 0.5 * (ws - 1.0);
        ra[r][1] = yc - 0.5 * (hs - 1.0);
        ra[r][2] = xc + 0.5 * (ws - 1.0);
        ra[r][3] = yc + 0.5 * (hs - 1.0);
    }
    int k = 0;
    for (int r = 0; r < 3; ++r) {
        double w2 = ra[r][2] - ra[r][0] + 1.0;
        double h2 = ra[r][3] - ra[r][1] + 1.0;
        double x2c = ra[r][0] + 0.5 * (w2 - 1.0);
        double y2c = ra[r][1] + 0.5 * (h2 - 1.0);
        for (int s = 0; s < 3; ++s) {
            double ws = w2 * scales[s], hs = h2 * scales[s];
            out[k*4+0] = (float)(x2c - 0.5 * (ws - 1.0));
            out[k*4+1] = (float)(y2c - 0.5 * (hs - 1.0));
            out[k*4+2] = (float)(x2c + 0.5 * (ws - 1.0));
            out[k*4+3] = (float)(y2c + 0.5 * (hs - 1.0));
            ++k;
        }
    }
}

__device__ __forceinline__ u32 sortable_key(float sc) {
    u32 sb = __float_as_uint(sc);
    return sb ^ ((sb & 0x80000000u) ? 0xFFFFFFFFu : 0x80000000u);
}

__device__ __forceinline__ u64 readlane64(u64 v, int l) {
    u32 lo = (u32)__builtin_amdgcn_readlane((int)(u32)v, l);
    u32 hi = (u32)__builtin_amdgcn_readlane((int)(u32)(v >> 32), l);
    return ((u64)hi << 32) | lo;
}

// 64-lane OR-reduce on the VALU pipe via DPP (rocPRIM pattern).
__device__ __forceinline__ u64 wave_or64_dpp(u64 v) {
    u32 lo = (u32)v, hi = (u32)(v >> 32);
#define DPPOR(x, ctrl) x |= (u32)__builtin_amdgcn_update_dpp(0, (int)(x), ctrl, 0xf, 0xf, false)
    DPPOR(lo, 0x111); DPPOR(lo, 0x112); DPPOR(lo, 0x114); DPPOR(lo, 0x118);
    DPPOR(lo, 0x142); DPPOR(lo, 0x143);
    DPPOR(hi, 0x111); DPPOR(hi, 0x112); DPPOR(hi, 0x114); DPPOR(hi, 0x118);
    DPPOR(hi, 0x142); DPPOR(hi, 0x143);
#undef DPPOR
    u32 rlo = (u32)__builtin_amdgcn_readlane((int)lo, 63);
    u32 rhi = (u32)__builtin_amdgcn_readlane((int)hi, 63);
    return ((u64)rhi << 32) | rlo;
}

// Shared decode: used by k_props (filter) and k_rank2 (winner gather).
// Same source + contract(off) in both -> bit-identical boxes.
__device__ __forceinline__ float4 decode_box(const float* __restrict__ deltas,
                                             const float* __restrict__ im_info,
                                             const Anchors& A, int b, int a, int p)
{
#pragma clang fp contract(off)
    int hh = p >> 7;        // / W
    int ww = p & 127;       // % W
    float sx = (float)(ww * 16);
    float sy = (float)(hh * 16);
    float ax1 = A.v[a*4+0] + sx;
    float ay1 = A.v[a*4+1] + sy;
    float ax2 = A.v[a*4+2] + sx;
    float ay2 = A.v[a*4+3] + sy;
    const float* dbase = deltas + ((size_t)(b*36 + a*4))*HW + p;
    float dx = dbase[0];
    float dy = dbase[HW];
    float dw = dbase[2*HW];
    float dh = dbase[3*HW];
    float aw = ax2 - ax1 + 1.0f;
    float ah = ay2 - ay1 + 1.0f;
    float cx = ax1 + 0.5f*aw;
    float cy = ay1 + 0.5f*ah;
    float pcx = dx*aw + cx;
    float pcy = dy*ah + cy;
    float ew = (float)exp((double)dw);   // correctly-rounded f32 exp
    float eh = (float)exp((double)dh);
    float pw = ew * aw;
    float ph = eh * ah;
    float x1 = pcx - 0.5f*pw;
    float y1 = pcy - 0.5f*ph;
    float x2 = pcx + 0.5f*pw;
    float y2 = pcy + 0.5f*ph;
    float hmax = im_info[b*3+0] - 1.0f;
    float wmax = im_info[b*3+1] - 1.0f;
    x1 = fmaxf(x1, 0.0f); y1 = fmaxf(y1, 0.0f);
    x2 = fmaxf(x2, 0.0f); y2 = fmaxf(y2, 0.0f);
    x1 = fminf(x1, wmax); y1 = fminf(y1, hmax);
    x2 = fminf(x2, wmax); y2 = fminf(y2, hmax);
    return make_float4(x1, y1, x2, y2);
}

// ---------------- kernel 1: decode + filter + key store + 12-bit LDS histogram ----------------
__global__ void k_props(const float* __restrict__ scores,
                        const float* __restrict__ deltas,
                        const float* __restrict__ im_info,
                        const float* __restrict__ valid_range,
                        Anchors A,
                        u32* __restrict__ fkeys,
                        u32* __restrict__ hist12)    // [NREP][NB][NBINS]
{
#pragma clang fp contract(off)
    __shared__ u32 lh[NBINS];   // 16 KB
    int tid = threadIdx.x;
#pragma unroll
    for (int i = 0; i < NBINS/256; ++i) lh[tid + i*256] = 0;
    __syncthreads();

    int n = blockIdx.x * 256 + tid;
    int b = n / NPB;
    int r = n - b*NPB;
    int a = r / HW;
    int p = r - a*HW;

    float4 bx = decode_box(deltas, im_info, A, b, a, p);
    float sc = scores[((size_t)(b*18 + 9 + a))*HW + p];
    float area = (bx.z - bx.x) * (bx.w - bx.y);
    float v0 = valid_range[b*2+0], v1 = valid_range[b*2+1];
    if (area < v0*v0 || area > v1*v1) sc = -1.0f;

    u32 key = sortable_key(sc);
    fkeys[n] = key;
    atomicAdd(&lh[key >> 20], 1u);
    __syncthreads();

    int rep = blockIdx.x & (NREP-1);
    u32* gh = hist12 + ((size_t)rep*NB + b)*NBINS;
#pragma unroll
    for (int i = 0; i < NBINS/256; ++i) {
        u32 v = lh[tid + i*256];
        if (v) atomicAdd(&gh[tid + i*256], v);
    }
}

// ---------------- kernel 2: 12-bit threshold via suffix-scan (1024 threads/batch) ----------------
__global__ void k_findT(const u32* __restrict__ hist12, u32* __restrict__ thresh12)
{
    __shared__ u32 sfx[1024];
    int b = blockIdx.x, t = threadIdx.x;    // 1024 threads; thread owns bins 4t..4t+3
    u32 bin0 = 0, bin1 = 0, bin2 = 0, bin3 = 0;
    for (int rr = 0; rr < NREP; ++rr) {
        const u32* h = hist12 + ((size_t)rr*NB + b)*NBINS + t*4;
        bin0 += h[0]; bin1 += h[1]; bin2 += h[2]; bin3 += h[3];
    }
    u32 s4 = bin0 + bin1 + bin2 + bin3;
    sfx[t] = s4;
    __syncthreads();
    for (int d = 1; d < 1024; d <<= 1) {
        u32 add = (t + d < 1024) ? sfx[t + d] : 0u;
        __syncthreads();
        sfx[t] += add;
        __syncthreads();
    }
    u32 above = (t < 1023) ? sfx[t+1] : 0u;     // sum of bins >= 4(t+1)
    u32 c3 = bin3 + above;
    u32 c2 = bin2 + c3;
    u32 c1 = bin1 + c2;
    u32 c0 = bin0 + c1;
    if (c3 >= TOPN && above < TOPN) thresh12[b] = (u32)(t*4 + 3);
    if (c2 >= TOPN && c3    < TOPN) thresh12[b] = (u32)(t*4 + 2);
    if (c1 >= TOPN && c2    < TOPN) thresh12[b] = (u32)(t*4 + 1);
    if (c0 >= TOPN && c1    < TOPN) thresh12[b] = (u32)(t*4 + 0);
}

// ---------------- kernel 3: emit candidates (replicated wave-aggregated counters) ----------------
// Order within cand is nondeterministic; k_rank2's rank-sort canonicalizes.
__global__ void k_emit(const u32* __restrict__ fkeys,
                       const u32* __restrict__ thresh12,
                       u32* __restrict__ ccntRep,     // [NB*NREPL] stride-16 u32 (64B lines)
                       u64* __restrict__ cand)        // [NB][NREPL][REPCAP]
{
    int tid = threadIdx.x;
    int n = blockIdx.x * 256 + tid;
    int b = n / NPB;
    int r = n - b*NPB;
    int a = r / HW;
    int p = r - a*HW;
    u32 key = fkeys[n];
    bool cond = (key >> 20) >= thresh12[b];
    u64 m = __ballot(cond);
    int lane = tid & 63;
    int rep = blockIdx.x & (NREPL-1);
    if (cond) {
        int leader = __ffsll((unsigned long long)m) - 1;
        u32 base = 0;
        if (lane == leader)
            base = atomicAdd(&ccntRep[(b*NREPL + rep)*16], (u32)__popcll(m));
        base = (u32)__shfl((int)base, leader);
        u32 pos = base + (u32)__popcll(m & ((1ull << lane) - 1ull));
        if (pos < REPCAP) {
            u32 t = (u32)(p*NA + a);               // reference flat index
            cand[((size_t)b*NREPL + rep)*REPCAP + pos] = ((u64)key << 32) | (u32)(~t);
        }
    }
}

// ---------------- kernel 4: region-compact + global rank-sort in LDS + winner re-decode ----------------
__global__ void k_rank2(const u64* __restrict__ cand, const u32* __restrict__ ccntRep,
                        const float* __restrict__ deltas,
                        const float* __restrict__ im_info,
                        Anchors A,
                        float4* __restrict__ topk)
{
    __shared__ u64 kk[CANDCAP];   // 64 KB
    __shared__ u32 ps[256];
    __shared__ u32 rcnt[32];
    __shared__ u32 roff[33];
    int b = blockIdx.y;
    int tid = threadIdx.x;
    if (tid < 32) {
        u32 c = ccntRep[(b*NREPL + tid)*16];
        rcnt[tid] = (c > REPCAP) ? REPCAP : c;
    }
    __syncthreads();
    if (tid == 0) {
        u32 acc = 0;
        for (int i = 0; i < 32; ++i) { roff[i] = acc; acc += rcnt[i]; }
        roff[32] = (acc > CANDCAP) ? CANDCAP : acc;
    }
    __syncthreads();
    u32 N = roff[32];
    if ((u32)(blockIdx.x * 64) >= N) return;    // whole block idle
    for (int rr = 0; rr < 32; ++rr) {
        u32 len = rcnt[rr], base = roff[rr];
        const u64* src = cand + ((size_t)b*NREPL + rr)*REPCAP;
        for (u32 i = tid; i < len; i += 256) {
            u32 g = base + i;
            if (g < CANDCAP) kk[g] = src[i];
        }
    }
    __syncthreads();
    int kl = tid & 63, seg = tid >> 6;
    u32 ki = (u32)(blockIdx.x * 64 + kl);
    u64 mykey = (ki < N) ? kk[ki] : ~0ull;
    u32 segN = (N + 3) >> 2;
    u32 s0 = seg * segN;
    u32 s1 = s0 + segN; if (s1 > N) s1 = N;
    u32 pr = 0;
    u32 i = s0;
    for (; i + 16 <= s1; i += 16) {
        u64 v0 = kk[i+0],  v1 = kk[i+1],  v2 = kk[i+2],  v3 = kk[i+3];
        u64 v4 = kk[i+4],  v5 = kk[i+5],  v6 = kk[i+6],  v7 = kk[i+7];
        u64 v8 = kk[i+8],  v9 = kk[i+9],  va = kk[i+10], vb = kk[i+11];
        u64 vc = kk[i+12], vd = kk[i+13], ve = kk[i+14], vf = kk[i+15];
        pr += (v0 > mykey) + (v1 > mykey) + (v2 > mykey) + (v3 > mykey);
        pr += (v4 > mykey) + (v5 > mykey) + (v6 > mykey) + (v7 > mykey);
        pr += (v8 > mykey) + (v9 > mykey) + (va > mykey) + (vb > mykey);
        pr += (vc > mykey) + (vd > mykey) + (ve > mykey) + (vf > mykey);
    }
    for (; i < s1; ++i) pr += (kk[i] > mykey) ? 1u : 0u;
    ps[tid] = pr;
    __syncthreads();
    if (seg == 0 && ki < N) {
        u32 rank = ps[kl] + ps[kl+64] + ps[kl+128] + ps[kl+192];
        if (rank < TOPN) {
            u32 t = ~((u32)mykey);
            int a = (int)(t % 9u);
            int p = (int)(t / 9u);
            topk[(size_t)b*MROWS + rank] = decode_box(deltas, im_info, A, b, a, p);
        }
    }
}

// ---------------- kernel 5: suppression-mask tiles — UPPER TRIANGLE ONLY ----------------
__global__ void k_mask(const float4* __restrict__ topk, u64* __restrict__ masksT)
{
#pragma clang fp contract(off)
    int L = blockIdx.x;            // 0..TRI-1
    int b = blockIdx.y;
    int ti = (int)((2.0*NTILE + 1.0 -
                    sqrt((2.0*NTILE + 1.0)*(2.0*NTILE + 1.0) - 8.0*(double)L)) * 0.5);
    while ((ti+1)*NTILE - ((ti+1)*ti)/2 <= L) ++ti;          // fixup sqrt rounding
    while (ti*NTILE - (ti*(ti-1))/2 > L) --ti;
    int tj = ti + (L - (ti*NTILE - (ti*(ti-1))/2));

    int r = threadIdx.x;           // 0..63
    int i = ti*64 + r;
    __shared__ float4 cb[64];
    __shared__ float  ca[64];
    u64 word = 0;
    {
        int jj = tj*64 + r;
        float4 cbox = (jj < TOPN) ? topk[(size_t)b*MROWS + jj] : make_float4(0,0,0,0);
        cb[r] = cbox;
        ca[r] = (cbox.z - cbox.x + 1.0f) * (cbox.w - cbox.y + 1.0f);
        __syncthreads();
        if (i < TOPN) {
            float4 rb = topk[(size_t)b*MROWS + i];
            float rarea = (rb.z - rb.x + 1.0f) * (rb.w - rb.y + 1.0f);
            for (int q = 0; q < 64; ++q) {
                float4 cc = cb[q];
                float iw = fminf(rb.z, cc.z) - fmaxf(rb.x, cc.x) + 1.0f;
                float ih = fminf(rb.w, cc.w) - fmaxf(rb.y, cc.y) + 1.0f;
                iw = fmaxf(iw, 0.0f); ih = fmaxf(ih, 0.0f);
                float inter = iw * ih;
                float uni = (rarea + ca[q]) - inter;
                float iou = inter / uni;       // IEEE fp32 division, like numpy
                if (iou > 0.7f) word |= (1ULL << q);
            }
            int nvalid = TOPN - tj*64;
            if (nvalid < 64) word &= ((1ULL << nvalid) - 1ULL);
            if (ti == tj) {
                u64 cm = (r == 63) ? ~0ULL : ((1ULL << (r + 1)) - 1ULL);
                word &= ~cm;                   // enforce j > i
            }
        }
    }
    masksT[((size_t)(b*64 + tj))*RST + i] = word;
}

// ---------------- kernel 6: greedy scan — FOUR-WAVE, one barrier per chunk ----------------
// wave0: late-term (own-SGPR kmask_prev select + DPP) + SALU closure + masks.
// wave1: staging only (PSTORE column c+1, PLOAD column c+2).
// wave2/3: each pre-reduces half of wpart(c+1) from its own pf2 registers
//          (1-chunk-ahead loads) during the parallel phase -> wpart[(c+1)&1].
// NOTE: w must pass through readfirstlane before the "+s" asm (LDS reads are
// VGPR; VGPR->SGPR copies are illegal without explicit readlane).
#define NMS_PLOAD(cc) { \
    int cm = ((cc) > 62) ? 62 : (cc); \
    const u64* colp = mb + (size_t)cm*RST; \
    _Pragma("unroll") \
    for (int k = 0; k < NBLK; ++k) \
        if (k <= cm) pf[k] = colp[(size_t)k*64 + lane]; \
}

#define NMS_PSTORE(cc, BUF) { \
    int cm = ((cc) > 62) ? 62 : (cc); \
    int wmax = (cm < NBLK-1) ? cm+1 : NBLK; \
    _Pragma("unroll") \
    for (int k = 0; k < NBLK; ++k) \
        if (k < wmax) (BUF)[k*64 + lane] = pf[k]; \
}

// load half-range blocks [H0, H0+HBLK) of column cc into pf2
#define NMS_PLOAD2(cc, H0) { \
    int cm = ((cc) > 62) ? 62 : (cc); \
    const u64* colp = mb + (size_t)cm*RST; \
    _Pragma("unroll") \
    for (int k = 0; k < HBLK; ++k) \
        if ((H0) + k <= cm) pf2[k] = colp[(size_t)((H0) + k)*64 + lane]; \
}

__global__ __launch_bounds__(256, 1) void k_nms(const u64* __restrict__ masksT,
                      const float4* __restrict__ topk,
                      float* __restrict__ out)
{
    int b = blockIdx.x;
    int tid = threadIdx.x;
    int lane = tid & 63;
    int wid = tid >> 6;            // 0=closure 1=stager 2/3=acc halves

    __shared__ u64 colbuf[2][NBLK*64];   // 43 KB double-buffered column history
    __shared__ u32 kmexp[64][64];        // per-(chunk,row) keep select mask
    __shared__ u64 kmw[64];              // per-chunk keep bitmask (valid-masked)
    __shared__ u64 wpart[2][2];          // [c&1][halfA/halfB] pre-reduced history OR
    __shared__ int exitf;

    if (wid == 0) {
        kmw[lane] = 0ull;
#pragma unroll
        for (int k = 0; k < 16; ++k) kmexp[k][lane] = 0u;
    } else {
#pragma unroll
        for (int k = 0; k < 16; ++k) kmexp[wid*16 + k][lane] = 0u;
    }
    if (tid == 0) {
        wpart[0][0] = 0ull; wpart[0][1] = 0ull;
        wpart[1][0] = 0ull; wpart[1][1] = 0ull;
        exitf = 0;
    }

    const u64* mb = masksT + (size_t)b*64*RST;

    u64 pf[NBLK];       // wave1 only (live registers gated by wid)
    u64 pf2[HBLK];      // wave2/3 only
    int h0 = (wid == 3) ? HBLK : 0;

    if (wid == 0) {
        // fill this batch's output with [b,0,0,0,0] while wave1 stages
        float* ob = out + (size_t)b*POSTN*5;
        for (int e = lane; e < POSTN*5; e += 64)
            ob[e] = ((e % 5) == 0) ? (float)b : 0.0f;
    } else if (wid == 1) {
        NMS_PLOAD(0)
        NMS_PSTORE(0, colbuf[0])
        NMS_PLOAD(1)
    } else {
        NMS_PLOAD2(1, h0)           // column 1 (consumed at chunk 1)
    }

    u64 kmask_prev = 0ull;          // wave0: kept-mask of previous chunk (uniform)
    int kcnt = 0;
    for (int c = 0; c < 63; ++c) {
        int cur = c & 1;
        __syncthreads();                           // B1: kmexp[c-1], colbuf[cur], wpart[cur] ready
        if (exitf) break;
        if (wid == 0) {
            u64 wv0 = wpart[cur][0] | wpart[cur][1]; // history k <= c-2 (pre-reduced, uniform)
            if (c > 0) {
                // late term k = c-1: select by own kmask_prev bit, DPP-reduce
                u64 ltD = (c-1 < NBLK) ? colbuf[cur][(c-1)*64 + lane]
                                       : mb[(size_t)c*RST + (size_t)(c-1)*64 + lane];
                u64 sel = ((kmask_prev >> lane) & 1ull) ? ltD : 0ull;
                wv0 |= wave_or64_dpp(sel);
            }
            // move the (uniform) value into SGPRs for the "+s" asm closure
            u32 wlo_ = (u32)__builtin_amdgcn_readfirstlane((int)(u32)wv0);
            u32 whi_ = (u32)__builtin_amdgcn_readfirstlane((int)(u32)(wv0 >> 32));
            u64 w = ((u64)whi_ << 32) | wlo_;
            u64 D = (c < NBLK) ? colbuf[cur][c*64 + lane]
                               : mb[(size_t)c*RST + (size_t)c*64 + lane];
#pragma unroll
            for (int g = 0; g < 4; ++g) {
                u64 drs[16];
#pragma unroll
                for (int j = 0; j < 16; ++j) drs[j] = readlane64(D, g*16 + j);
#pragma unroll
                for (int j = 0; j < 16; ++j) {
                    u64 t;
                    asm("s_bitcmp1_b64 %[w], %[rr]\n\t"
                        "s_cselect_b64 %[t], 0, %[d]\n\t"
                        "s_or_b64 %[w], %[w], %[t]"
                        : [w]"+s"(w), [t]"=&s"(t)
                        : [d]"s"(drs[j]), [rr]"i"(g*16 + j)
                        : "scc");
                }
            }
            u64 kmask = ~w & ((c < 62) ? ~0ull : 0xFFFFFFFFull);
            kcnt += __popcll(kmask);
            if (lane == 0) {
                kmw[c] = kmask;
                if (kcnt >= POSTN || c == 62) exitf = 1;
            }
            kmexp[c][lane] = ((u32)((kmask >> lane) & 1ull)) ? ~0u : 0u;
            kmask_prev = kmask;
        } else if (wid == 1) {
            NMS_PSTORE(c+1, colbuf[cur^1])
            NMS_PLOAD(c+2)
        } else {
            // pre-reduce this half of wpart(c+1): k in [h0, min(c, h0+HBLK))
            u64 ap = 0;
            int km = (c < NBLK) ? c : NBLK;
#pragma unroll
            for (int k = 0; k < HBLK; ++k) {
                if (h0 + k < km) {
                    u32 mk = kmexp[h0 + k][lane];
                    ap |= pf2[k] & (((u64)mk << 32) | mk);
                }
            }
            if (wid == 3) {                        // fallback k in [NBLK, c) (exit<=42 => never)
                int ccl = (c+1 > 62) ? 62 : (c+1);
                for (int k = NBLK; k < c; ++k) {
                    u32 mk = kmexp[k][lane];
                    u64 v2 = mb[(size_t)ccl*RST + (size_t)k*64 + lane];
                    ap |= v2 & (((u64)mk << 32) | mk);
                }
            }
            u64 wr = wave_or64_dpp(ap);
            if (lane == 0) wpart[cur^1][wid-2] = wr;
            NMS_PLOAD2(c+2, h0)                    // for wpart(c+2), consumed next chunk
        }
    }

    // output enumeration by wave0 only (kmw[c]=0 for unprocessed chunks)
    if (wid == 0) {
        u64 keepw = kmw[lane];
        int cnt = __popcll(keepw);
        int pre = cnt;
        for (int d = 1; d < 64; d <<= 1) {
            int t = __shfl_up(pre, d);
            if (lane >= d) pre += t;
        }
        int excl = pre - cnt;
        asm volatile("s_waitcnt vmcnt(0)" ::: "memory");  // fill stores drained
        u64 wv = keepw; int rk = excl;
        while (wv) {
            int bpos = __ffsll((unsigned long long)wv) - 1;
            wv &= wv - 1;
            if (rk < POSTN) {
                int i = lane*64 + bpos;
                float4 bx = topk[(size_t)b*MROWS + i];
                float* o = out + ((size_t)b*POSTN + rk)*5;
                o[1] = bx.x; o[2] = bx.y; o[3] = bx.z; o[4] = bx.w;
            }
            ++rk;
        }
    }
}

// ---------------- launch ----------------
extern "C" void kernel_launch(void* const* d_in, const int* in_sizes, int n_in,
                              void* d_out, int out_size, void* d_ws, size_t ws_size,
                              hipStream_t stream)
{
    const float* scores  = (const float*)d_in[0];
    const float* deltas  = (const float*)d_in[1];
    const float* im_info = (const float*)d_in[2];
    const float* vrange  = (const float*)d_in[3];
    float* out = (float*)d_out;

    char* ws = (char*)d_ws;
    size_t off = 0;
    auto alloc = [&](size_t bytes) -> void* {
        void* ptr = ws + off;
        off += (bytes + 255) & ~(size_t)255;
        return ptr;
    };
    u32*   fkeys   = (u32*)   alloc((size_t)NB*NPB*sizeof(u32));           // 2.36 MB
    u64*   cand    = (u64*)   alloc((size_t)NB*NREPL*REPCAP*sizeof(u64));  // 1 MB
    float4* topk   = (float4*)alloc((size_t)NB*MROWS*sizeof(float4));      // 256 KB
    u64*   masksT  = (u64*)   alloc((size_t)NB*64*RST*sizeof(u64));        // 8.52 MB
    // zeroed region (single memset): hist12 | ccntRep
    u32*   hist12  = (u32*)   alloc((size_t)NREP*NB*NBINS*sizeof(u32));    // 256 KB
    u32*   ccntRep = (u32*)   alloc((size_t)NB*NREPL*16*sizeof(u32));      // 8 KB
    // outputs written every run (no init needed)
    u32*   thresh12= (u32*)   alloc(256);

    Anchors A;
    gen_anchors(A.v);

    size_t zbytes = (char*)ccntRep + (size_t)NB*NREPL*16*sizeof(u32) - (char*)hist12;
    (void)hipMemsetAsync(hist12, 0, zbytes, stream);

    int total = NB*NPB;
    int blocks = (total + 255)/256;    // 2304, exact (NPB % 256 == 0)
    k_props<<<blocks, 256, 0, stream>>>(scores, deltas, im_info, vrange, A, fkeys, hist12);
    k_findT<<<NB, 1024, 0, stream>>>(hist12, thresh12);
    k_emit<<<blocks, 256, 0, stream>>>(fkeys, thresh12, ccntRep, cand);
    dim3 rgrid(CANDCAP/64, NB);
    k_rank2<<<rgrid, 256, 0, stream>>>(cand, ccntRep, deltas, im_info, A, topk);
    dim3 mgrid(TRI, NB);
    k_mask<<<mgrid, 64, 0, stream>>>(topk, masksT);
    k_nms<<<NB, 256, 0, stream>>>(masksT, topk, out);
}